// Round 9
// baseline (381.078 us; speedup 1.0000x reference)
//
#include <hip/hip_runtime.h>
#include <cstddef>
#include <cstdint>

static constexpr int Dm   = 1024;
static constexpr int Hh   = 16;
static constexpr int HDd  = 64;
static constexpr int FFd  = 4096;
static constexpr int Ls   = 2048;
static constexpr int Nb   = 2;
static constexpr int Mrows = Nb * Ls;   // 4096

typedef short bf16x8 __attribute__((ext_vector_type(8)));
typedef float f32x4  __attribute__((ext_vector_type(4)));

#if __has_builtin(__builtin_amdgcn_exp2f)
#define EXP2(x) __builtin_amdgcn_exp2f(x)
#else
#define EXP2(x) exp2f(x)
#endif

__device__ __forceinline__ ushort f2b(float f) {        // RNE (pre-pass)
    uint32_t u = __builtin_bit_cast(uint32_t, f);
    u = (u + 0x7FFFu + ((u >> 16) & 1u)) >> 16;
    return (ushort)u;
}
__device__ __forceinline__ ushort f2bf(float f) {       // fast round-half-up
    return (ushort)((__builtin_bit_cast(uint32_t, f) + 0x8000u) >> 16);
}
__device__ __forceinline__ float b2f(ushort b) {
    return __builtin_bit_cast(float, (uint32_t)b << 16);
}

__device__ __forceinline__ void gl2lds16(const ushort* g, ushort* l) {
    __builtin_amdgcn_global_load_lds(
        (const __attribute__((address_space(1))) void*)g,
        (__attribute__((address_space(3))) void*)l, 16, 0, 0);
}

// Coalesced C-store: lanes (l, l^1) exchange packed rows via shfl_xor(1);
// even lane stores rows 0,1 / odd lane rows 2,3 as dwords covering 2 cols.
template <int RELU>
__device__ __forceinline__ void pack_store_pair(
    ushort* __restrict__ C, int N, int m0, int n, int lane,
    const f32x4 a, float bv)
{
    float v0 = a[0] + bv, v1 = a[1] + bv, v2 = a[2] + bv, v3 = a[3] + bv;
    if (RELU) {
        v0 = fmaxf(v0, 0.f); v1 = fmaxf(v1, 0.f);
        v2 = fmaxf(v2, 0.f); v3 = fmaxf(v3, 0.f);
    }
    uint32_t a01 = (uint32_t)f2bf(v0) | ((uint32_t)f2bf(v1) << 16);
    uint32_t a23 = (uint32_t)f2bf(v2) | ((uint32_t)f2bf(v3) << 16);
    uint32_t x01 = (uint32_t)__shfl_xor((int)a01, 1);
    uint32_t x23 = (uint32_t)__shfl_xor((int)a23, 1);
    const bool ev = (lane & 1) == 0;
    const uint32_t low  = ev ? a01 : x23;   // value of the lower column
    const uint32_t high = ev ? x01 : a23;   // value of the higher column
    const uint32_t dA = (low & 0xFFFFu) | (high << 16);
    const uint32_t dB = (low >> 16) | (high & 0xFFFF0000u);
    const int rb = ev ? 0 : 2;
    const int nc = n - (lane & 1);
    *(uint32_t*)(C + (size_t)(m0 + rb) * N + nc)     = dA;
    *(uint32_t*)(C + (size_t)(m0 + rb + 1) * N + nc) = dB;
}

// ---------------------------------------------------------------------------
__global__ __launch_bounds__(256) void convert_bf16(
    const float* __restrict__ src, ushort* __restrict__ dst, int n)
{
    int i = (blockIdx.x * 256 + threadIdx.x) * 4;
    if (i >= n) return;
    float4 v = *(const float4*)(src + i);
    uint2 o;
    o.x = (uint32_t)f2b(v.x) | ((uint32_t)f2b(v.y) << 16);
    o.y = (uint32_t)f2b(v.z) | ((uint32_t)f2b(v.w) << 16);
    *(uint2*)(dst + i) = o;
}

// ---------------------------------------------------------------------------
__global__ __launch_bounds__(256) void transpose_bf16(
    const float* __restrict__ src, ushort* __restrict__ dst, int K, int N)
{
    __shared__ float t[32][33];
    const int k0 = blockIdx.y * 32, n0 = blockIdx.x * 32;
    const int tx = threadIdx.x & 31, ty = threadIdx.x >> 5;
    #pragma unroll
    for (int i = 0; i < 4; ++i)
        t[ty + i * 8][tx] = src[(size_t)(k0 + ty + i * 8) * N + n0 + tx];
    __syncthreads();
    #pragma unroll
    for (int i = 0; i < 4; ++i)
        dst[(size_t)(n0 + ty + i * 8) * K + k0 + tx] = f2b(t[tx][ty + i * 8]);
}

// ---------------------------------------------------------------------------
// bf16 MFMA GEMM, double-buffered LDS, ONE barrier per K-iter.
// C[M,N] = A[M,K] @ Bt[N,K]^T + bias. 128 x TN tile (TN=128|96|64), 256 thr.
// TN=96 (qkv): grid 1024 = 4 blocks/CU. B-staging: full-wave call rows 0-63
// + wave<2 call 64-95. VOUT: per-16col-fragment branch between Q/K pack-store
// and V scatter into vT[n][h][d][key].
// SPLITK>1: grid.z slices; bf16 partials at Cb + z*M*N (contiguous slots).
// ff2 uses TN=128 + SPLITK=4: the 128x128 tile (m97 shape, 16 MFMA per
// 8 ds_read per K-iter) at 4 blocks/CU — TN=64 ran at only ~505 TF.
// ---------------------------------------------------------------------------
template <int TN, int RELU, int VOUT, int SPLITK>
__global__ __launch_bounds__(256) void gemm_mfma(
    const ushort* __restrict__ A, const ushort* __restrict__ Bt,
    const float* __restrict__ bias,
    ushort* __restrict__ Cb, ushort* __restrict__ vT, int M, int N, int K)
{
    constexpr int NT  = TN / 32;                 // B n-frags per wave
    constexpr int BSZ = TN * 32;                 // Bs shorts per buffer
    __shared__ __align__(16) ushort As[2 * 128 * 32];
    __shared__ __align__(16) ushort Bs[2 * BSZ];

    const int tid  = threadIdx.x;
    int bx, by;
    {
        const int gx = gridDim.x;
        const int nwg = gx * gridDim.y;
        const int lin = blockIdx.y * gx + blockIdx.x;
        const int swz = (lin & 7) * (nwg >> 3) + (lin >> 3);
        by = swz / gx; bx = swz - by * gx;
    }
    const int bm   = by * 128, bn = bx * TN;
    const int wave = tid >> 6, lane = tid & 63;
    const int wm = (wave & 1) * 64;
    const int wn = (wave >> 1) * (TN / 2);
    const int lr = lane & 15, lq = lane >> 4;

    const int KS   = K / SPLITK;                 // K per slice
    const int Koff = (SPLITK > 1) ? blockIdx.z * KS : 0;

    const int rr = wave * 16 + (lane >> 2);
    const int sg = lane & 3;
    const ushort* Ag = A  + (size_t)(bm + rr) * K + Koff + sg * 8;
    const ushort* Bg = Bt + (size_t)(bn + rr) * K + Koff + sg * 8;

    f32x4 acc[4][NT];
    #pragma unroll
    for (int i = 0; i < 4; ++i)
        #pragma unroll
        for (int j = 0; j < NT; ++j)
            acc[i][j] = (f32x4){0.f, 0.f, 0.f, 0.f};

    // prologue: stage k=0 into buffer 0
    gl2lds16(Ag,                  As + wave * 512);
    gl2lds16(Ag + (size_t)64 * K, As + 2048 + wave * 512);
    gl2lds16(Bg,                  Bs + wave * 512);
    if (TN == 128)
        gl2lds16(Bg + (size_t)64 * K, Bs + 2048 + wave * 512);
    if (TN == 96) {
        if (wave < 2)
            gl2lds16(Bg + (size_t)64 * K, Bs + 2048 + wave * 512);
    }

    int ib = 0;
    for (int k0 = 0; k0 < KS; k0 += 32, ib ^= 1) {
        __syncthreads();   // drains vmcnt: buffer ib is ready; buffer ib^1 free
        if (k0 + 32 < KS) {
            const int nb = ib ^ 1;
            gl2lds16(Ag + k0 + 32,                  As + nb * 4096 + wave * 512);
            gl2lds16(Ag + k0 + 32 + (size_t)64 * K, As + nb * 4096 + 2048 + wave * 512);
            gl2lds16(Bg + k0 + 32,                  Bs + nb * BSZ + wave * 512);
            if (TN == 128)
                gl2lds16(Bg + k0 + 32 + (size_t)64 * K, Bs + nb * BSZ + 2048 + wave * 512);
            if (TN == 96) {
                if (wave < 2)
                    gl2lds16(Bg + k0 + 32 + (size_t)64 * K, Bs + nb * BSZ + 2048 + wave * 512);
            }
        }

        const ushort* Ar = As + ib * 4096;
        const ushort* Br = Bs + ib * BSZ;
        bf16x8 af[4], bf[NT];
        #pragma unroll
        for (int mt = 0; mt < 4; ++mt)
            af[mt] = *(const bf16x8*)(Ar + (wm + mt * 16 + lr) * 32 + lq * 8);
        #pragma unroll
        for (int nt = 0; nt < NT; ++nt)
            bf[nt] = *(const bf16x8*)(Br + (wn + nt * 16 + lr) * 32 + lq * 8);

        #pragma unroll
        for (int mt = 0; mt < 4; ++mt)
            #pragma unroll
            for (int nt = 0; nt < NT; ++nt)
                acc[mt][nt] = __builtin_amdgcn_mfma_f32_16x16x32_bf16(
                    af[mt], bf[nt], acc[mt][nt], 0, 0, 0);
    }

    // Epilogue. C/D layout: col = lane&15, row = (lane>>4)*4 + r
    if (SPLITK > 1) {
        ushort* Cp = Cb + (size_t)blockIdx.z * M * N;
        #pragma unroll
        for (int nt = 0; nt < NT; ++nt) {
            const int n = bn + wn + nt * 16 + lr;
            #pragma unroll
            for (int mt = 0; mt < 4; ++mt)
                pack_store_pair<0>(Cp, N, bm + wm + mt * 16 + lq * 4, n, lane,
                                   acc[mt][nt], 0.0f);
        }
        return;
    }
    if (VOUT) {
        const int batch = bm >> 11;
        #pragma unroll
        for (int nt = 0; nt < NT; ++nt) {
            const int n = bn + wn + nt * 16 + lr;
            const float bv = bias[n];
            if (bn + wn + nt * 16 >= 2 * Dm) {
                // V fragment -> vT[n][h][d][key]; merge lq pairs via
                // shfl_xor(16) so each lane stores 8 contiguous keys (16B).
                const int col = n - 2 * Dm;          // 0..1023
                const int h = col >> 6, d = col & 63;
                uint2 p4[4];
                #pragma unroll
                for (int mt = 0; mt < 4; ++mt) {
                    p4[mt].x = (uint32_t)f2bf(acc[mt][nt][0] + bv) |
                               ((uint32_t)f2bf(acc[mt][nt][1] + bv) << 16);
                    p4[mt].y = (uint32_t)f2bf(acc[mt][nt][2] + bv) |
                               ((uint32_t)f2bf(acc[mt][nt][3] + bv) << 16);
                }
                uint2 q4[4];
                #pragma unroll
                for (int mt = 0; mt < 4; ++mt) {
                    q4[mt].x = (uint32_t)__shfl_xor((int)p4[mt].x, 16);
                    q4[mt].y = (uint32_t)__shfl_xor((int)p4[mt].y, 16);
                }
                ushort* drow = vT + (((size_t)(batch * Hh + h)) * HDd + d) * Ls;
                const bool evq = (lq & 1) == 0;
                #pragma unroll
                for (int t = 0; t < 2; ++t) {
                    const int mt = (evq ? 0 : 2) + t;
                    const int key = (bm + wm + mt * 16 + (lq & ~1) * 4) & (Ls - 1);
                    uint4 w;
                    if (evq) w = (uint4){p4[mt].x, p4[mt].y, q4[mt].x, q4[mt].y};
                    else     w = (uint4){q4[mt].x, q4[mt].y, p4[mt].x, p4[mt].y};
                    *(uint4*)(drow + key) = w;
                }
            } else {
                #pragma unroll
                for (int mt = 0; mt < 4; ++mt)
                    pack_store_pair<0>(Cb, N, bm + wm + mt * 16 + lq * 4, n, lane,
                                       acc[mt][nt], bv);
            }
        }
        return;
    }
    #pragma unroll
    for (int nt = 0; nt < NT; ++nt) {
        const int n = bn + wn + nt * 16 + lr;
        const float bv = bias[n];
        #pragma unroll
        for (int mt = 0; mt < 4; ++mt)
            pack_store_pair<RELU>(Cb, N, bm + wm + mt * 16 + lq * 4, n, lane,
                                  acc[mt][nt], bv);
    }
}

// ---------------------------------------------------------------------------
// MFMA flash attention, S^T formulation, no-max softmax, KV-SPLIT 2.
// P stays entirely in registers (V key-axis permuted in LDS).
// ---------------------------------------------------------------------------
__global__ __launch_bounds__(256) void attn_mfma(
    const ushort* __restrict__ qkv, const ushort* __restrict__ vT,
    float* __restrict__ npart, float* __restrict__ dpart)
{
    const int tid = threadIdx.x, wave = tid >> 6, lane = tid & 63;
    const int lr = lane & 15, lq = lane >> 4;
    // grid (16,16,4): swizzle (nwg=1024) -> XCD c gets 128 contiguous tiles
    int bx, h, z;
    {
        const int lin = (blockIdx.z * 16 + blockIdx.y) * 16 + blockIdx.x;
        const int swz = (lin & 7) * 128 + (lin >> 3);
        bx = swz & 15; h = (swz >> 4) & 15; z = swz >> 8;
    }
    const int n = z >> 1, kv = z & 1;
    const int kt0 = kv * (Ls / 2);
    const int q0 = bx * 128 + wave * 32;
    const size_t RS = 3 * Dm;
    const ushort* base  = qkv + (size_t)n * Ls * RS;
    const ushort* vbase = vT + (size_t)(n * Hh + h) * HDd * Ls;

    __shared__ __align__(16) ushort Kb[64 * 72];      // [key][d]
    __shared__ __align__(16) ushort Vt[64 * 72];      // [d][slot] (pi-permuted keys)

    // Q fragments (B-layout: n=lr=q, k=lq*8+j=d), prescaled 0.125*log2(e)
    bf16x8 qf[2][2];                                   // [ks][qh]
    {
        const float c = 0.18033688011112042f;
        #pragma unroll
        for (int qh = 0; qh < 2; ++qh) {
            const ushort* qg = base + (size_t)(q0 + qh * 16 + lr) * RS + h * HDd + lq * 8;
            bf16x8 t0 = *(const bf16x8*)(qg);
            bf16x8 t1 = *(const bf16x8*)(qg + 32);
            #pragma unroll
            for (int j = 0; j < 8; ++j) {
                qf[0][qh][j] = (short)f2b(b2f((ushort)t0[j]) * c);
                qf[1][qh][j] = (short)f2b(b2f((ushort)t1[j]) * c);
            }
        }
    }

    // all-ones A fragment for the denominator MFMA (1.0bf16 = 0x3F80)
    bf16x8 onesf;
    #pragma unroll
    for (int j = 0; j < 8; ++j) onesf[j] = (short)0x3F80;
    const f32x4 z4 = (f32x4){0.f, 0.f, 0.f, 0.f};

    f32x4 o[4][2];                                     // [dt][qh]
    #pragma unroll
    for (int dt = 0; dt < 4; ++dt)
        #pragma unroll
        for (int qh = 0; qh < 2; ++qh)
            o[dt][qh] = (f32x4){0.f, 0.f, 0.f, 0.f};
    f32x4 dacc[2];                                     // denominator acc
    dacc[0] = (f32x4){0.f, 0.f, 0.f, 0.f};
    dacc[1] = (f32x4){0.f, 0.f, 0.f, 0.f};

    const int srow = tid >> 2, ssg = tid & 3;
    const ushort* kg = base + (size_t)srow * RS + Dm + h * HDd;
    const ushort* vg = vbase + (size_t)srow * Ls;

    // V slot-permutation write bases
    const int sA = (((2 * ssg) & 3) * 8) + (((ssg >> 1) & 1) * 4);
    const int sB = (((2 * ssg + 1) & 3) * 8) + (((ssg >> 1) & 1) * 4);

    // prefetch first tile of this kv half into registers
    int4 ka = *(const int4*)(kg + (size_t)kt0 * RS + ssg * 8);
    int4 kb = *(const int4*)(kg + (size_t)kt0 * RS + (ssg + 4) * 8);
    int4 va = *(const int4*)(vg + kt0 + ssg * 8);
    int4 vb = *(const int4*)(vg + kt0 + (ssg + 4) * 8);

    for (int kt = kt0; kt < kt0 + Ls / 2; kt += 64) {
        __syncthreads();            // all reads of previous tile done
        *(int4*)(Kb + srow * 72 + ssg * 8)       = ka;
        *(int4*)(Kb + srow * 72 + (ssg + 4) * 8) = kb;
        {
            ushort* vrow = Vt + srow * 72;
            *(uint2*)(vrow + sA)      = (uint2){(uint32_t)va.x, (uint32_t)va.y};
            *(uint2*)(vrow + sB)      = (uint2){(uint32_t)va.z, (uint32_t)va.w};
            *(uint2*)(vrow + 32 + sA) = (uint2){(uint32_t)vb.x, (uint32_t)vb.y};
            *(uint2*)(vrow + 32 + sB) = (uint2){(uint32_t)vb.z, (uint32_t)vb.w};
        }
        __syncthreads();

        // T14: issue next tile's global loads; latency hides under compute
        if (kt + 64 < kt0 + Ls / 2) {
            const ushort* kp = kg + (size_t)(kt + 64) * RS;
            const ushort* vp = vg + (kt + 64);
            ka = *(const int4*)(kp + ssg * 8);
            kb = *(const int4*)(kp + (ssg + 4) * 8);
            va = *(const int4*)(vp + ssg * 8);
            vb = *(const int4*)(vp + (ssg + 4) * 8);
        }

        // S^T = K Q^T : [64 key][32 q], exp2 domain
        f32x4 s[4][2];
        #pragma unroll
        for (int ks = 0; ks < 2; ++ks)
            #pragma unroll
            for (int mt = 0; mt < 4; ++mt) {
                bf16x8 kf = *(const bf16x8*)(Kb + (mt * 16 + lr) * 72 + ks * 32 + lq * 8);
                #pragma unroll
                for (int qh = 0; qh < 2; ++qh)
                    s[mt][qh] = __builtin_amdgcn_mfma_f32_16x16x32_bf16(
                        kf, qf[ks][qh], ks == 0 ? z4 : s[mt][qh], 0, 0, 0);
            }

        // p = exp2(s), pack bf16 pairs with v_cvt_pk_bf16_f32
        uint2 pb[4][2];
        #pragma unroll
        for (int mt = 0; mt < 4; ++mt)
            #pragma unroll
            for (int qh = 0; qh < 2; ++qh) {
                float p0 = EXP2(s[mt][qh][0]);
                float p1 = EXP2(s[mt][qh][1]);
                float p2 = EXP2(s[mt][qh][2]);
                float p3 = EXP2(s[mt][qh][3]);
                uint32_t w0, w1;
                asm("v_cvt_pk_bf16_f32 %0, %1, %2" : "=v"(w0) : "v"(p0), "v"(p1));
                asm("v_cvt_pk_bf16_f32 %0, %1, %2" : "=v"(w1) : "v"(p2), "v"(p3));
                pb[mt][qh].x = w0;
                pb[mt][qh].y = w1;
            }

        // O^T += V^T P^T over permuted slots; P fragment = register concat.
        #pragma unroll
        for (int ks = 0; ks < 2; ++ks) {
            bf16x8 pf[2];
            #pragma unroll
            for (int qh = 0; qh < 2; ++qh) {
                uint4 u = (uint4){pb[2 * ks][qh].x, pb[2 * ks][qh].y,
                                  pb[2 * ks + 1][qh].x, pb[2 * ks + 1][qh].y};
                pf[qh] = __builtin_bit_cast(bf16x8, u);
            }
            #pragma unroll
            for (int dt = 0; dt < 4; ++dt) {
                bf16x8 vf = *(const bf16x8*)(Vt + (dt * 16 + lr) * 72 + ks * 32 + lq * 8);
                #pragma unroll
                for (int qh = 0; qh < 2; ++qh)
                    o[dt][qh] = __builtin_amdgcn_mfma_f32_16x16x32_bf16(
                        vf, pf[qh], o[dt][qh], 0, 0, 0);
            }
            #pragma unroll
            for (int qh = 0; qh < 2; ++qh)
                dacc[qh] = __builtin_amdgcn_mfma_f32_16x16x32_bf16(
                    onesf, pf[qh], dacc[qh], 0, 0, 0);
        }
    }

    // write f32 numerator partials [kv][n][q][h*64+d] and denominators
    const int idx = kv * Nb + n;
    #pragma unroll
    for (int qh = 0; qh < 2; ++qh) {
        float* nrow = npart + ((size_t)idx * Ls + q0 + qh * 16 + lr) * Dm + h * HDd;
        #pragma unroll
        for (int dt = 0; dt < 4; ++dt) {
            float4 o4 = {o[dt][qh][0], o[dt][qh][1], o[dt][qh][2], o[dt][qh][3]};
            *(float4*)(nrow + dt * 16 + lq * 4) = o4;
        }
        if (lane < 16)
            dpart[((size_t)idx * Hh + h) * Ls + q0 + qh * 16 + lane] = dacc[qh][0];
    }
}

// ---------------------------------------------------------------------------
// attnb[row] = (n0 + n1) / (d0 + d1), bf16.
// ---------------------------------------------------------------------------
__global__ __launch_bounds__(256) void attn_combine(
    const float* __restrict__ npart, const float* __restrict__ dpart,
    ushort* __restrict__ out)
{
    const int row = blockIdx.x;            // n*Ls + q
    const int tid = threadIdx.x;
    const int n = row >> 11, q = row & (Ls - 1);
    const int h = tid >> 4;                // 16 threads x 4 floats = 64 d per head

    const size_t b0 = ((size_t)(0 * Nb + n) * Ls + q) * Dm;
    const size_t b1 = ((size_t)(1 * Nb + n) * Ls + q) * Dm;
    float4 a = ((const float4*)(npart + b0))[tid];
    float4 b = ((const float4*)(npart + b1))[tid];
    const float d0 = dpart[((size_t)(0 * Nb + n) * Hh + h) * Ls + q];
    const float d1 = dpart[((size_t)(1 * Nb + n) * Hh + h) * Ls + q];
    const float inv = 1.0f / (d0 + d1);

    ushort4 ob;
    ob.x = f2bf((a.x + b.x) * inv);
    ob.y = f2bf((a.y + b.y) * inv);
    ob.z = f2bf((a.z + b.z) * inv);
    ob.w = f2bf((a.w + b.w) * inv);
    *(ushort4*)(out + (size_t)row * Dm + tid * 4) = ob;
}

// ---------------------------------------------------------------------------
// out = LayerNorm(sum_{p<NP} part[p] + bias + other) * gamma + beta.
// part slots are contiguous 8MB bf16 buffers at part + p*Mrows*Dm.
// ---------------------------------------------------------------------------
template <int NP, int OTHER_BF16, int OUT_F32>
__global__ __launch_bounds__(256) void addn_ln(
    const ushort* __restrict__ part, const void* __restrict__ other,
    const float* __restrict__ bias,
    const float* __restrict__ gamma, const float* __restrict__ beta,
    float* __restrict__ outf, ushort* __restrict__ outb)
{
    const int row = blockIdx.x;
    const int tid = threadIdx.x;

    float4 bv = ((const float4*)bias)[tid];
    float v[4];
    if (OTHER_BF16) {
        ushort4 u = ((const ushort4*)((const ushort*)other + (size_t)row * Dm))[tid];
        v[0] = b2f(u.x) + bv.x; v[1] = b2f(u.y) + bv.y;
        v[2] = b2f(u.z) + bv.z; v[3] = b2f(u.w) + bv.w;
    } else {
        float4 f = ((const float4*)((const float*)other + (size_t)row * Dm))[tid];
        v[0] = f.x + bv.x; v[1] = f.y + bv.y; v[2] = f.z + bv.z; v[3] = f.w + bv.w;
    }
    #pragma unroll
    for (int pp = 0; pp < NP; ++pp) {
        ushort4 u = ((const ushort4*)(part + (size_t)pp * Mrows * Dm
                                           + (size_t)row * Dm))[tid];
        v[0] += b2f(u.x); v[1] += b2f(u.y); v[2] += b2f(u.z); v[3] += b2f(u.w);
    }

    float s  = v[0] + v[1] + v[2] + v[3];
    float sq = v[0]*v[0] + v[1]*v[1] + v[2]*v[2] + v[3]*v[3];

    __shared__ float red[8];
    #pragma unroll
    for (int off = 32; off > 0; off >>= 1) {
        s  += __shfl_down(s, off);
        sq += __shfl_down(sq, off);
    }
    const int wv = tid >> 6;
    if ((tid & 63) == 0) { red[wv] = s; red[4 + wv] = sq; }
    __syncthreads();
    s  = red[0] + red[1] + red[2] + red[3];
    sq = red[4] + red[5] + red[6] + red[7];

    const float mu  = s * (1.0f / Dm);
    const float var = sq * (1.0f / Dm) - mu * mu;
    const float inv = rsqrtf(var + 1e-5f);

    const float4 g  = ((const float4*)gamma)[tid];
    const float4 be = ((const float4*)beta)[tid];
    float ov[4];
    ov[0] = (v[0] - mu) * inv * g.x + be.x;
    ov[1] = (v[1] - mu) * inv * g.y + be.y;
    ov[2] = (v[2] - mu) * inv * g.z + be.z;
    ov[3] = (v[3] - mu) * inv * g.w + be.w;
    if (OUT_F32) {
        float4 o4 = {ov[0], ov[1], ov[2], ov[3]};
        ((float4*)(outf + (size_t)row * Dm))[tid] = o4;
    } else {
        uint2 ob;
        ob.x = (uint32_t)f2bf(ov[0]) | ((uint32_t)f2bf(ov[1]) << 16);
        ob.y = (uint32_t)f2bf(ov[2]) | ((uint32_t)f2bf(ov[3]) << 16);
        *(uint2*)(outb + (size_t)row * Dm + tid * 4) = ob;
    }
}

// ---------------------------------------------------------------------------
extern "C" void kernel_launch(void* const* d_in, const int* in_sizes, int n_in,
                              void* d_out, int out_size, void* d_ws, size_t ws_size,
                              hipStream_t stream)
{
    const float* x     = (const float*)d_in[0];
    const float* w_qkv = (const float*)d_in[1];
    const float* b_qkv = (const float*)d_in[2];
    const float* w_o   = (const float*)d_in[3];
    const float* b_o   = (const float*)d_in[4];
    const float* g1    = (const float*)d_in[5];
    const float* be1   = (const float*)d_in[6];
    const float* w1    = (const float*)d_in[7];
    const float* b1    = (const float*)d_in[8];
    const float* w2    = (const float*)d_in[9];
    const float* b2    = (const float*)d_in[10];
    const float* g2    = (const float*)d_in[11];
    const float* be2   = (const float*)d_in[12];
    float* out = (float*)d_out;

    // Workspace. part4 = 4 contiguous 8MB bf16 partial slots:
    //   slots 0,1: proj / ff2 split-K partials (slot0 start doubles as dpart)
    //   slot 2:    attnb  (dead once proj consumed it -> ff2 partial z=2)
    //   slot 3:    xb     (dead once qkv consumed it  -> ff2 partial z=3)
    char* p = (char*)d_ws;
    ushort* part4 = (ushort*)p;  p += (size_t)4 * Mrows * Dm * 2;   // 32 MB
    ushort* qkvb  = (ushort*)p;  p += (size_t)Mrows * 3 * Dm * 2;
    ushort* hb    = (ushort*)p;  p += (size_t)Mrows * Dm * 2;
    ushort* ffb   = (ushort*)p;  p += (size_t)Mrows * FFd * 2;
    ushort* wqkvT = (ushort*)p;  p += (size_t)(3 * Dm) * Dm * 2;
    ushort* woT   = (ushort*)p;  p += (size_t)Dm * Dm * 2;
    ushort* w1T   = (ushort*)p;  p += (size_t)FFd * Dm * 2;
    ushort* w2T   = (ushort*)p;  p += (size_t)Dm * FFd * 2;
    ushort* vTg   = (ushort*)p;  p += (size_t)Mrows * Dm * 2;

    ushort* attnb = part4 + (size_t)2 * Mrows * Dm;
    ushort* xb    = part4 + (size_t)3 * Mrows * Dm;
    float* npart = (float*)ffb;     // 2 * Mrows * Dm * 4B = 32 MB == ffb size
    float* dpart = (float*)part4;   // 512 KB, dead once proj partials written

    convert_bf16<<<dim3(Mrows * Dm / 1024), dim3(256), 0, stream>>>(x, xb, Mrows * Dm);
    transpose_bf16<<<dim3(3 * Dm / 32, Dm / 32), dim3(256), 0, stream>>>(w_qkv, wqkvT, Dm, 3 * Dm);
    transpose_bf16<<<dim3(Dm / 32, Dm / 32),     dim3(256), 0, stream>>>(w_o, woT, Dm, Dm);
    transpose_bf16<<<dim3(FFd / 32, Dm / 32),    dim3(256), 0, stream>>>(w1, w1T, Dm, FFd);
    transpose_bf16<<<dim3(Dm / 32, FFd / 32),    dim3(256), 0, stream>>>(w2, w2T, FFd, Dm);

    // qkv = x @ w_qkv + b_qkv; TN=96 -> 4 blocks/CU. Q,K -> qkvb, V -> vTg.
    gemm_mfma<96, 0, 1, 1><<<dim3(3 * Dm / 96, Mrows / 128), dim3(256), 0, stream>>>(
        xb, wqkvT, b_qkv, qkvb, vTg, Mrows, 3 * Dm, Dm);

    // attn: KV-split 2, f32 numerator/denominator partials
    attn_mfma<<<dim3(Ls / 128, Hh, 2 * Nb), dim3(256), 0, stream>>>(qkvb, vTg, npart, dpart);
    attn_combine<<<dim3(Mrows), dim3(256), 0, stream>>>(npart, dpart, attnb);

    // proj partials = attn @ w_o (split-K 2 -> slots 0,1)
    gemm_mfma<64, 0, 0, 2><<<dim3(Dm / 64, Mrows / 128, 2), dim3(256), 0, stream>>>(
        attnb, woT, nullptr, part4, nullptr, Mrows, Dm, Dm);

    // h = LN(p0 + p1 + b_o + x) -> bf16
    addn_ln<2, 0, 0><<<dim3(Mrows), dim3(256), 0, stream>>>(
        part4, x, b_o, g1, be1, nullptr, hb);

    // ff = relu(h @ w1 + b1) (bf16)
    gemm_mfma<128, 1, 0, 1><<<dim3(FFd / 128, Mrows / 128), dim3(256), 0, stream>>>(
        hb, w1T, b1, ffb, nullptr, Mrows, FFd, Dm);

    // ff2 partials = ff @ w2 (split-K 4, TN=128: 128x128 tile, 4 blocks/CU)
    gemm_mfma<128, 0, 0, 4><<<dim3(Dm / 128, Mrows / 128, 4), dim3(256), 0, stream>>>(
        ffb, w2T, nullptr, part4, nullptr, Mrows, Dm, FFd);

    // out = LN(p0 + p1 + p2 + p3 + b2 + h) -> fp32
    addn_ln<4, 1, 1><<<dim3(Mrows), dim3(256), 0, stream>>>(
        part4, hb, b2, g2, be2, out, nullptr);
}

// Round 11
// 368.895 us; speedup vs baseline: 1.0330x; 1.0330x over previous
//
#include <hip/hip_runtime.h>
#include <cstddef>
#include <cstdint>

static constexpr int Dm   = 1024;
static constexpr int Hh   = 16;
static constexpr int HDd  = 64;
static constexpr int FFd  = 4096;
static constexpr int Ls   = 2048;
static constexpr int Nb   = 2;
static constexpr int Mrows = Nb * Ls;   // 4096

typedef short bf16x8 __attribute__((ext_vector_type(8)));
typedef float f32x4  __attribute__((ext_vector_type(4)));

#if __has_builtin(__builtin_amdgcn_exp2f)
#define EXP2(x) __builtin_amdgcn_exp2f(x)
#else
#define EXP2(x) exp2f(x)
#endif

__device__ __forceinline__ ushort f2b(float f) {        // RNE (pre-pass)
    uint32_t u = __builtin_bit_cast(uint32_t, f);
    u = (u + 0x7FFFu + ((u >> 16) & 1u)) >> 16;
    return (ushort)u;
}
__device__ __forceinline__ ushort f2bf(float f) {       // fast round-half-up
    return (ushort)((__builtin_bit_cast(uint32_t, f) + 0x8000u) >> 16);
}
__device__ __forceinline__ float b2f(ushort b) {
    return __builtin_bit_cast(float, (uint32_t)b << 16);
}

__device__ __forceinline__ void gl2lds16(const ushort* g, ushort* l) {
    __builtin_amdgcn_global_load_lds(
        (const __attribute__((address_space(1))) void*)g,
        (__attribute__((address_space(3))) void*)l, 16, 0, 0);
}

// Coalesced C-store: lanes (l, l^1) exchange packed rows via shfl_xor(1);
// even lane stores rows 0,1 / odd lane rows 2,3 as dwords covering 2 cols.
template <int RELU>
__device__ __forceinline__ void pack_store_pair(
    ushort* __restrict__ C, int N, int m0, int n, int lane,
    const f32x4 a, float bv)
{
    float v0 = a[0] + bv, v1 = a[1] + bv, v2 = a[2] + bv, v3 = a[3] + bv;
    if (RELU) {
        v0 = fmaxf(v0, 0.f); v1 = fmaxf(v1, 0.f);
        v2 = fmaxf(v2, 0.f); v3 = fmaxf(v3, 0.f);
    }
    uint32_t a01 = (uint32_t)f2bf(v0) | ((uint32_t)f2bf(v1) << 16);
    uint32_t a23 = (uint32_t)f2bf(v2) | ((uint32_t)f2bf(v3) << 16);
    uint32_t x01 = (uint32_t)__shfl_xor((int)a01, 1);
    uint32_t x23 = (uint32_t)__shfl_xor((int)a23, 1);
    const bool ev = (lane & 1) == 0;
    const uint32_t low  = ev ? a01 : x23;   // value of the lower column
    const uint32_t high = ev ? x01 : a23;   // value of the higher column
    const uint32_t dA = (low & 0xFFFFu) | (high << 16);
    const uint32_t dB = (low >> 16) | (high & 0xFFFF0000u);
    const int rb = ev ? 0 : 2;
    const int nc = n - (lane & 1);
    *(uint32_t*)(C + (size_t)(m0 + rb) * N + nc)     = dA;
    *(uint32_t*)(C + (size_t)(m0 + rb + 1) * N + nc) = dB;
}

// ---------------------------------------------------------------------------
// Fused prep: convert x -> bf16 (blocks [0,4096)) and the 4 weight transposes
// (blocks [4096,16384)), dispatched by blockIdx range (block-uniform branch).
// Replaces 5 kernel launches with 1.
// ---------------------------------------------------------------------------
__global__ __launch_bounds__(256) void prep(
    const float* __restrict__ x, ushort* __restrict__ xb,
    const float* __restrict__ w_qkv, ushort* __restrict__ wqkvT,
    const float* __restrict__ w_o, ushort* __restrict__ woT,
    const float* __restrict__ w1, ushort* __restrict__ w1T,
    const float* __restrict__ w2, ushort* __restrict__ w2T)
{
    __shared__ float t[32][33];
    const int bid = blockIdx.x;
    const int tidx = threadIdx.x;
    if (bid < 4096) {                       // convert: 4096 x 1024 elems
        const int i = bid * 1024 + tidx * 4;
        float4 v = *(const float4*)(x + i);
        uint2 o;
        o.x = (uint32_t)f2b(v.x) | ((uint32_t)f2b(v.y) << 16);
        o.y = (uint32_t)f2b(v.z) | ((uint32_t)f2b(v.w) << 16);
        *(uint2*)(xb + i) = o;
        return;
    }
    const float* src; ushort* dst; int K, N, r;
    if (bid < 7168)       { r = bid - 4096;  src = w_qkv; dst = wqkvT; K = Dm;  N = 3 * Dm; }
    else if (bid < 8192)  { r = bid - 7168;  src = w_o;   dst = woT;   K = Dm;  N = Dm;  }
    else if (bid < 12288) { r = bid - 8192;  src = w1;    dst = w1T;   K = Dm;  N = FFd; }
    else                  { r = bid - 12288; src = w2;    dst = w2T;   K = FFd; N = Dm;  }
    const int gx = N / 32;
    const int bx = r % gx, by = r / gx;
    const int k0 = by * 32, n0 = bx * 32;
    const int tx = tidx & 31, ty = tidx >> 5;
    #pragma unroll
    for (int i = 0; i < 4; ++i)
        t[ty + i * 8][tx] = src[(size_t)(k0 + ty + i * 8) * N + n0 + tx];
    __syncthreads();
    #pragma unroll
    for (int i = 0; i < 4; ++i)
        dst[(size_t)(n0 + ty + i * 8) * K + k0 + tx] = f2b(t[tx][ty + i * 8]);
}

// ---------------------------------------------------------------------------
// bf16 MFMA GEMM, double-buffered LDS, ONE barrier per K-iter.
// C[M,N] = A[M,K] @ Bt[N,K]^T + bias. 128 x TN tile (TN=128|96|64), 256 thr.
// TN=96 (qkv): grid 1024 = 4 blocks/CU. VOUT: per-16col-fragment branch
// between Q/K pack-store and V scatter into vT[n][h][d][key].
// SPLITK>1: grid.z slices; bf16 partials at Cb + z*M*N (contiguous slots).
// ---------------------------------------------------------------------------
template <int TN, int RELU, int VOUT, int SPLITK>
__global__ __launch_bounds__(256) void gemm_mfma(
    const ushort* __restrict__ A, const ushort* __restrict__ Bt,
    const float* __restrict__ bias,
    ushort* __restrict__ Cb, ushort* __restrict__ vT, int M, int N, int K)
{
    constexpr int NT  = TN / 32;                 // B n-frags per wave
    constexpr int BSZ = TN * 32;                 // Bs shorts per buffer
    __shared__ __align__(16) ushort As[2 * 128 * 32];
    __shared__ __align__(16) ushort Bs[2 * BSZ];

    const int tid  = threadIdx.x;
    int bx, by;
    {
        const int gx = gridDim.x;
        const int nwg = gx * gridDim.y;
        const int lin = blockIdx.y * gx + blockIdx.x;
        const int swz = (lin & 7) * (nwg >> 3) + (lin >> 3);
        by = swz / gx; bx = swz - by * gx;
    }
    const int bm   = by * 128, bn = bx * TN;
    const int wave = tid >> 6, lane = tid & 63;
    const int wm = (wave & 1) * 64;
    const int wn = (wave >> 1) * (TN / 2);
    const int lr = lane & 15, lq = lane >> 4;

    const int KS   = K / SPLITK;                 // K per slice
    const int Koff = (SPLITK > 1) ? blockIdx.z * KS : 0;

    const int rr = wave * 16 + (lane >> 2);
    const int sg = lane & 3;
    const ushort* Ag = A  + (size_t)(bm + rr) * K + Koff + sg * 8;
    const ushort* Bg = Bt + (size_t)(bn + rr) * K + Koff + sg * 8;

    f32x4 acc[4][NT];
    #pragma unroll
    for (int i = 0; i < 4; ++i)
        #pragma unroll
        for (int j = 0; j < NT; ++j)
            acc[i][j] = (f32x4){0.f, 0.f, 0.f, 0.f};

    // prologue: stage k=0 into buffer 0
    gl2lds16(Ag,                  As + wave * 512);
    gl2lds16(Ag + (size_t)64 * K, As + 2048 + wave * 512);
    gl2lds16(Bg,                  Bs + wave * 512);
    if (TN == 128)
        gl2lds16(Bg + (size_t)64 * K, Bs + 2048 + wave * 512);
    if (TN == 96) {
        if (wave < 2)
            gl2lds16(Bg + (size_t)64 * K, Bs + 2048 + wave * 512);
    }

    int ib = 0;
    for (int k0 = 0; k0 < KS; k0 += 32, ib ^= 1) {
        __syncthreads();   // drains vmcnt: buffer ib is ready; buffer ib^1 free
        if (k0 + 32 < KS) {
            const int nb = ib ^ 1;
            gl2lds16(Ag + k0 + 32,                  As + nb * 4096 + wave * 512);
            gl2lds16(Ag + k0 + 32 + (size_t)64 * K, As + nb * 4096 + 2048 + wave * 512);
            gl2lds16(Bg + k0 + 32,                  Bs + nb * BSZ + wave * 512);
            if (TN == 128)
                gl2lds16(Bg + k0 + 32 + (size_t)64 * K, Bs + nb * BSZ + 2048 + wave * 512);
            if (TN == 96) {
                if (wave < 2)
                    gl2lds16(Bg + k0 + 32 + (size_t)64 * K, Bs + nb * BSZ + 2048 + wave * 512);
            }
        }

        const ushort* Ar = As + ib * 4096;
        const ushort* Br = Bs + ib * BSZ;
        bf16x8 af[4], bf[NT];
        #pragma unroll
        for (int mt = 0; mt < 4; ++mt)
            af[mt] = *(const bf16x8*)(Ar + (wm + mt * 16 + lr) * 32 + lq * 8);
        #pragma unroll
        for (int nt = 0; nt < NT; ++nt)
            bf[nt] = *(const bf16x8*)(Br + (wn + nt * 16 + lr) * 32 + lq * 8);

        #pragma unroll
        for (int mt = 0; mt < 4; ++mt)
            #pragma unroll
            for (int nt = 0; nt < NT; ++nt)
                acc[mt][nt] = __builtin_amdgcn_mfma_f32_16x16x32_bf16(
                    af[mt], bf[nt], acc[mt][nt], 0, 0, 0);
    }

    // Epilogue. C/D layout: col = lane&15, row = (lane>>4)*4 + r
    if (SPLITK > 1) {
        ushort* Cp = Cb + (size_t)blockIdx.z * M * N;
        #pragma unroll
        for (int nt = 0; nt < NT; ++nt) {
            const int n = bn + wn + nt * 16 + lr;
            #pragma unroll
            for (int mt = 0; mt < 4; ++mt)
                pack_store_pair<0>(Cp, N, bm + wm + mt * 16 + lq * 4, n, lane,
                                   acc[mt][nt], 0.0f);
        }
        return;
    }
    if (VOUT) {
        const int batch = bm >> 11;
        #pragma unroll
        for (int nt = 0; nt < NT; ++nt) {
            const int n = bn + wn + nt * 16 + lr;
            const float bv = bias[n];
            if (bn + wn + nt * 16 >= 2 * Dm) {
                // V fragment -> vT[n][h][d][key]; merge lq pairs via
                // shfl_xor(16) so each lane stores 8 contiguous keys (16B).
                const int col = n - 2 * Dm;          // 0..1023
                const int h = col >> 6, d = col & 63;
                uint2 p4[4];
                #pragma unroll
                for (int mt = 0; mt < 4; ++mt) {
                    p4[mt].x = (uint32_t)f2bf(acc[mt][nt][0] + bv) |
                               ((uint32_t)f2bf(acc[mt][nt][1] + bv) << 16);
                    p4[mt].y = (uint32_t)f2bf(acc[mt][nt][2] + bv) |
                               ((uint32_t)f2bf(acc[mt][nt][3] + bv) << 16);
                }
                uint2 q4[4];
                #pragma unroll
                for (int mt = 0; mt < 4; ++mt) {
                    q4[mt].x = (uint32_t)__shfl_xor((int)p4[mt].x, 16);
                    q4[mt].y = (uint32_t)__shfl_xor((int)p4[mt].y, 16);
                }
                ushort* drow = vT + (((size_t)(batch * Hh + h)) * HDd + d) * Ls;
                const bool evq = (lq & 1) == 0;
                #pragma unroll
                for (int t = 0; t < 2; ++t) {
                    const int mt = (evq ? 0 : 2) + t;
                    const int key = (bm + wm + mt * 16 + (lq & ~1) * 4) & (Ls - 1);
                    uint4 w;
                    if (evq) w = (uint4){p4[mt].x, p4[mt].y, q4[mt].x, q4[mt].y};
                    else     w = (uint4){q4[mt].x, q4[mt].y, p4[mt].x, p4[mt].y};
                    *(uint4*)(drow + key) = w;
                }
            } else {
                #pragma unroll
                for (int mt = 0; mt < 4; ++mt)
                    pack_store_pair<0>(Cb, N, bm + wm + mt * 16 + lq * 4, n, lane,
                                       acc[mt][nt], bv);
            }
        }
        return;
    }
    #pragma unroll
    for (int nt = 0; nt < NT; ++nt) {
        const int n = bn + wn + nt * 16 + lr;
        const float bv = bias[n];
        #pragma unroll
        for (int mt = 0; mt < 4; ++mt)
            pack_store_pair<RELU>(Cb, N, bm + wm + mt * 16 + lq * 4, n, lane,
                                  acc[mt][nt], bv);
    }
}

// ---------------------------------------------------------------------------
// MFMA flash attention, S^T formulation, no-max softmax, KV-SPLIT 2
// (two blocks per q-tile, f32 numerator/denominator partials to global;
// attn_combine merges). P stays entirely in registers (V key-axis permuted
// in LDS, round 6). Known-good round-9 version.
// ---------------------------------------------------------------------------
__global__ __launch_bounds__(256) void attn_mfma(
    const ushort* __restrict__ qkv, const ushort* __restrict__ vT,
    float* __restrict__ npart, float* __restrict__ dpart)
{
    const int tid = threadIdx.x, wave = tid >> 6, lane = tid & 63;
    const int lr = lane & 15, lq = lane >> 4;
    // grid (16,16,4): swizzle (nwg=1024) -> XCD c gets 128 contiguous tiles
    int bx, h, z;
    {
        const int lin = (blockIdx.z * 16 + blockIdx.y) * 16 + blockIdx.x;
        const int swz = (lin & 7) * 128 + (lin >> 3);
        bx = swz & 15; h = (swz >> 4) & 15; z = swz >> 8;
    }
    const int n = z >> 1, kv = z & 1;
    const int kt0 = kv * (Ls / 2);
    const int q0 = bx * 128 + wave * 32;
    const size_t RS = 3 * Dm;
    const ushort* base  = qkv + (size_t)n * Ls * RS;
    const ushort* vbase = vT + (size_t)(n * Hh + h) * HDd * Ls;

    __shared__ __align__(16) ushort Kb[64 * 72];      // [key][d]
    __shared__ __align__(16) ushort Vt[64 * 72];      // [d][slot] (pi-permuted keys)

    // Q fragments (B-layout: n=lr=q, k=lq*8+j=d), prescaled 0.125*log2(e)
    bf16x8 qf[2][2];                                   // [ks][qh]
    {
        const float c = 0.18033688011112042f;
        #pragma unroll
        for (int qh = 0; qh < 2; ++qh) {
            const ushort* qg = base + (size_t)(q0 + qh * 16 + lr) * RS + h * HDd + lq * 8;
            bf16x8 t0 = *(const bf16x8*)(qg);
            bf16x8 t1 = *(const bf16x8*)(qg + 32);
            #pragma unroll
            for (int j = 0; j < 8; ++j) {
                qf[0][qh][j] = (short)f2b(b2f((ushort)t0[j]) * c);
                qf[1][qh][j] = (short)f2b(b2f((ushort)t1[j]) * c);
            }
        }
    }

    // all-ones A fragment for the denominator MFMA (1.0bf16 = 0x3F80)
    bf16x8 onesf;
    #pragma unroll
    for (int j = 0; j < 8; ++j) onesf[j] = (short)0x3F80;
    const f32x4 z4 = (f32x4){0.f, 0.f, 0.f, 0.f};

    f32x4 o[4][2];                                     // [dt][qh]
    #pragma unroll
    for (int dt = 0; dt < 4; ++dt)
        #pragma unroll
        for (int qh = 0; qh < 2; ++qh)
            o[dt][qh] = (f32x4){0.f, 0.f, 0.f, 0.f};
    f32x4 dacc[2];                                     // denominator acc
    dacc[0] = (f32x4){0.f, 0.f, 0.f, 0.f};
    dacc[1] = (f32x4){0.f, 0.f, 0.f, 0.f};

    const int srow = tid >> 2, ssg = tid & 3;
    const ushort* kg = base + (size_t)srow * RS + Dm + h * HDd;
    const ushort* vg = vbase + (size_t)srow * Ls;

    // V slot-permutation write bases
    const int sA = (((2 * ssg) & 3) * 8) + (((ssg >> 1) & 1) * 4);
    const int sB = (((2 * ssg + 1) & 3) * 8) + (((ssg >> 1) & 1) * 4);

    // prefetch first tile of this kv half into registers
    int4 ka = *(const int4*)(kg + (size_t)kt0 * RS + ssg * 8);
    int4 kb = *(const int4*)(kg + (size_t)kt0 * RS + (ssg + 4) * 8);
    int4 va = *(const int4*)(vg + kt0 + ssg * 8);
    int4 vb = *(const int4*)(vg + kt0 + (ssg + 4) * 8);

    for (int kt = kt0; kt < kt0 + Ls / 2; kt += 64) {
        __syncthreads();            // all reads of previous tile done
        *(int4*)(Kb + srow * 72 + ssg * 8)       = ka;
        *(int4*)(Kb + srow * 72 + (ssg + 4) * 8) = kb;
        {
            ushort* vrow = Vt + srow * 72;
            *(uint2*)(vrow + sA)      = (uint2){(uint32_t)va.x, (uint32_t)va.y};
            *(uint2*)(vrow + sB)      = (uint2){(uint32_t)va.z, (uint32_t)va.w};
            *(uint2*)(vrow + 32 + sA) = (uint2){(uint32_t)vb.x, (uint32_t)vb.y};
            *(uint2*)(vrow + 32 + sB) = (uint2){(uint32_t)vb.z, (uint32_t)vb.w};
        }
        __syncthreads();

        // T14: issue next tile's global loads; latency hides under compute
        if (kt + 64 < kt0 + Ls / 2) {
            const ushort* kp = kg + (size_t)(kt + 64) * RS;
            const ushort* vp = vg + (kt + 64);
            ka = *(const int4*)(kp + ssg * 8);
            kb = *(const int4*)(kp + (ssg + 4) * 8);
            va = *(const int4*)(vp + ssg * 8);
            vb = *(const int4*)(vp + (ssg + 4) * 8);
        }

        // S^T = K Q^T : [64 key][32 q], exp2 domain
        f32x4 s[4][2];
        #pragma unroll
        for (int ks = 0; ks < 2; ++ks)
            #pragma unroll
            for (int mt = 0; mt < 4; ++mt) {
                bf16x8 kf = *(const bf16x8*)(Kb + (mt * 16 + lr) * 72 + ks * 32 + lq * 8);
                #pragma unroll
                for (int qh = 0; qh < 2; ++qh)
                    s[mt][qh] = __builtin_amdgcn_mfma_f32_16x16x32_bf16(
                        kf, qf[ks][qh], ks == 0 ? z4 : s[mt][qh], 0, 0, 0);
            }

        // p = exp2(s), pack bf16 pairs with v_cvt_pk_bf16_f32
        uint2 pb[4][2];
        #pragma unroll
        for (int mt = 0; mt < 4; ++mt)
            #pragma unroll
            for (int qh = 0; qh < 2; ++qh) {
                float p0 = EXP2(s[mt][qh][0]);
                float p1 = EXP2(s[mt][qh][1]);
                float p2 = EXP2(s[mt][qh][2]);
                float p3 = EXP2(s[mt][qh][3]);
                uint32_t w0, w1;
                asm("v_cvt_pk_bf16_f32 %0, %1, %2" : "=v"(w0) : "v"(p0), "v"(p1));
                asm("v_cvt_pk_bf16_f32 %0, %1, %2" : "=v"(w1) : "v"(p2), "v"(p3));
                pb[mt][qh].x = w0;
                pb[mt][qh].y = w1;
            }

        // O^T += V^T P^T over permuted slots; P fragment = register concat.
        #pragma unroll
        for (int ks = 0; ks < 2; ++ks) {
            bf16x8 pf[2];
            #pragma unroll
            for (int qh = 0; qh < 2; ++qh) {
                uint4 u = (uint4){pb[2 * ks][qh].x, pb[2 * ks][qh].y,
                                  pb[2 * ks + 1][qh].x, pb[2 * ks + 1][qh].y};
                pf[qh] = __builtin_bit_cast(bf16x8, u);
            }
            #pragma unroll
            for (int dt = 0; dt < 4; ++dt) {
                bf16x8 vf = *(const bf16x8*)(Vt + (dt * 16 + lr) * 72 + ks * 32 + lq * 8);
                #pragma unroll
                for (int qh = 0; qh < 2; ++qh)
                    o[dt][qh] = __builtin_amdgcn_mfma_f32_16x16x32_bf16(
                        vf, pf[qh], o[dt][qh], 0, 0, 0);
            }
            #pragma unroll
            for (int qh = 0; qh < 2; ++qh)
                dacc[qh] = __builtin_amdgcn_mfma_f32_16x16x32_bf16(
                    onesf, pf[qh], dacc[qh], 0, 0, 0);
        }
    }

    // write f32 numerator partials [kv][n][q][h*64+d] and denominators
    const int idx = kv * Nb + n;
    #pragma unroll
    for (int qh = 0; qh < 2; ++qh) {
        float* nrow = npart + ((size_t)idx * Ls + q0 + qh * 16 + lr) * Dm + h * HDd;
        #pragma unroll
        for (int dt = 0; dt < 4; ++dt) {
            float4 o4 = {o[dt][qh][0], o[dt][qh][1], o[dt][qh][2], o[dt][qh][3]};
            *(float4*)(nrow + dt * 16 + lq * 4) = o4;
        }
        if (lane < 16)
            dpart[((size_t)idx * Hh + h) * Ls + q0 + qh * 16 + lane] = dacc[qh][0];
    }
}

// ---------------------------------------------------------------------------
// attnb[row] = (n0 + n1) / (d0 + d1), bf16.
// ---------------------------------------------------------------------------
__global__ __launch_bounds__(256) void attn_combine(
    const float* __restrict__ npart, const float* __restrict__ dpart,
    ushort* __restrict__ out)
{
    const int row = blockIdx.x;            // n*Ls + q
    const int tid = threadIdx.x;
    const int n = row >> 11, q = row & (Ls - 1);
    const int h = tid >> 4;                // 16 threads x 4 floats = 64 d per head

    const size_t b0 = ((size_t)(0 * Nb + n) * Ls + q) * Dm;
    const size_t b1 = ((size_t)(1 * Nb + n) * Ls + q) * Dm;
    float4 a = ((const float4*)(npart + b0))[tid];
    float4 b = ((const float4*)(npart + b1))[tid];
    const float d0 = dpart[((size_t)(0 * Nb + n) * Hh + h) * Ls + q];
    const float d1 = dpart[((size_t)(1 * Nb + n) * Hh + h) * Ls + q];
    const float inv = 1.0f / (d0 + d1);

    ushort4 ob;
    ob.x = f2bf((a.x + b.x) * inv);
    ob.y = f2bf((a.y + b.y) * inv);
    ob.z = f2bf((a.z + b.z) * inv);
    ob.w = f2bf((a.w + b.w) * inv);
    *(ushort4*)(out + (size_t)row * Dm + tid * 4) = ob;
}

// ---------------------------------------------------------------------------
// out = LayerNorm(sum_{p<NP} part[p] + bias + other) * gamma + beta.
// part slots are contiguous 8MB bf16 buffers at part + p*Mrows*Dm.
// ---------------------------------------------------------------------------
template <int NP, int OTHER_BF16, int OUT_F32>
__global__ __launch_bounds__(256) void addn_ln(
    const ushort* __restrict__ part, const void* __restrict__ other,
    const float* __restrict__ bias,
    const float* __restrict__ gamma, const float* __restrict__ beta,
    float* __restrict__ outf, ushort* __restrict__ outb)
{
    const int row = blockIdx.x;
    const int tid = threadIdx.x;

    float4 bv = ((const float4*)bias)[tid];
    float v[4];
    if (OTHER_BF16) {
        ushort4 u = ((const ushort4*)((const ushort*)other + (size_t)row * Dm))[tid];
        v[0] = b2f(u.x) + bv.x; v[1] = b2f(u.y) + bv.y;
        v[2] = b2f(u.z) + bv.z; v[3] = b2f(u.w) + bv.w;
    } else {
        float4 f = ((const float4*)((const float*)other + (size_t)row * Dm))[tid];
        v[0] = f.x + bv.x; v[1] = f.y + bv.y; v[2] = f.z + bv.z; v[3] = f.w + bv.w;
    }
    #pragma unroll
    for (int pp = 0; pp < NP; ++pp) {
        ushort4 u = ((const ushort4*)(part + (size_t)pp * Mrows * Dm
                                           + (size_t)row * Dm))[tid];
        v[0] += b2f(u.x); v[1] += b2f(u.y); v[2] += b2f(u.z); v[3] += b2f(u.w);
    }

    float s  = v[0] + v[1] + v[2] + v[3];
    float sq = v[0]*v[0] + v[1]*v[1] + v[2]*v[2] + v[3]*v[3];

    __shared__ float red[8];
    #pragma unroll
    for (int off = 32; off > 0; off >>= 1) {
        s  += __shfl_down(s, off);
        sq += __shfl_down(sq, off);
    }
    const int wv = tid >> 6;
    if ((tid & 63) == 0) { red[wv] = s; red[4 + wv] = sq; }
    __syncthreads();
    s  = red[0] + red[1] + red[2] + red[3];
    sq = red[4] + red[5] + red[6] + red[7];

    const float mu  = s * (1.0f / Dm);
    const float var = sq * (1.0f / Dm) - mu * mu;
    const float inv = rsqrtf(var + 1e-5f);

    const float4 g  = ((const float4*)gamma)[tid];
    const float4 be = ((const float4*)beta)[tid];
    float ov[4];
    ov[0] = (v[0] - mu) * inv * g.x + be.x;
    ov[1] = (v[1] - mu) * inv * g.y + be.y;
    ov[2] = (v[2] - mu) * inv * g.z + be.z;
    ov[3] = (v[3] - mu) * inv * g.w + be.w;
    if (OUT_F32) {
        float4 o4 = {ov[0], ov[1], ov[2], ov[3]};
        ((float4*)(outf + (size_t)row * Dm))[tid] = o4;
    } else {
        uint2 ob;
        ob.x = (uint32_t)f2bf(ov[0]) | ((uint32_t)f2bf(ov[1]) << 16);
        ob.y = (uint32_t)f2bf(ov[2]) | ((uint32_t)f2bf(ov[3]) << 16);
        *(uint2*)(outb + (size_t)row * Dm + tid * 4) = ob;
    }
}

// ---------------------------------------------------------------------------
extern "C" void kernel_launch(void* const* d_in, const int* in_sizes, int n_in,
                              void* d_out, int out_size, void* d_ws, size_t ws_size,
                              hipStream_t stream)
{
    const float* x     = (const float*)d_in[0];
    const float* w_qkv = (const float*)d_in[1];
    const float* b_qkv = (const float*)d_in[2];
    const float* w_o   = (const float*)d_in[3];
    const float* b_o   = (const float*)d_in[4];
    const float* g1    = (const float*)d_in[5];
    const float* be1   = (const float*)d_in[6];
    const float* w1    = (const float*)d_in[7];
    const float* b1    = (const float*)d_in[8];
    const float* w2    = (const float*)d_in[9];
    const float* b2    = (const float*)d_in[10];
    const float* g2    = (const float*)d_in[11];
    const float* be2   = (const float*)d_in[12];
    float* out = (float*)d_out;

    // Workspace. part4 = 4 contiguous 8MB bf16 partial slots:
    //   slots 0,1: proj / ff2 split-K partials (slot0 start doubles as dpart)
    //   slot 2:    attnb  (dead once proj consumed it -> ff2 partial z=2)
    //   slot 3:    xb     (dead once qkv consumed it  -> ff2 partial z=3)
    char* p = (char*)d_ws;
    ushort* part4 = (ushort*)p;  p += (size_t)4 * Mrows * Dm * 2;   // 32 MB
    ushort* qkvb  = (ushort*)p;  p += (size_t)Mrows * 3 * Dm * 2;
    ushort* hb    = (ushort*)p;  p += (size_t)Mrows * Dm * 2;
    ushort* ffb   = (ushort*)p;  p += (size_t)Mrows * FFd * 2;
    ushort* wqkvT = (ushort*)p;  p += (size_t)(3 * Dm) * Dm * 2;
    ushort* woT   = (ushort*)p;  p += (size_t)Dm * Dm * 2;
    ushort* w1T   = (ushort*)p;  p += (size_t)FFd * Dm * 2;
    ushort* w2T   = (ushort*)p;  p += (size_t)Dm * FFd * 2;
    ushort* vTg   = (ushort*)p;  p += (size_t)Mrows * Dm * 2;

    ushort* attnb = part4 + (size_t)2 * Mrows * Dm;
    ushort* xb    = part4 + (size_t)3 * Mrows * Dm;
    float* npart = (float*)ffb;     // 2 * Mrows * Dm * 4B = 32 MB == ffb size
    float* dpart = (float*)part4;   // 512 KB, dead once proj partials written

    // fused convert + weight transposes (1 launch instead of 5)
    prep<<<dim3(16384), dim3(256), 0, stream>>>(
        x, xb, w_qkv, wqkvT, w_o, woT, w1, w1T, w2, w2T);

    // qkv = x @ w_qkv + b_qkv; TN=96 -> 4 blocks/CU. Q,K -> qkvb, V -> vTg.
    gemm_mfma<96, 0, 1, 1><<<dim3(3 * Dm / 96, Mrows / 128), dim3(256), 0, stream>>>(
        xb, wqkvT, b_qkv, qkvb, vTg, Mrows, 3 * Dm, Dm);

    // attn: KV-split 2, f32 numerator/denominator partials
    attn_mfma<<<dim3(Ls / 128, Hh, 2 * Nb), dim3(256), 0, stream>>>(qkvb, vTg, npart, dpart);
    attn_combine<<<dim3(Mrows), dim3(256), 0, stream>>>(npart, dpart, attnb);

    // proj partials = attn @ w_o (split-K 2 -> slots 0,1)
    gemm_mfma<64, 0, 0, 2><<<dim3(Dm / 64, Mrows / 128, 2), dim3(256), 0, stream>>>(
        attnb, woT, nullptr, part4, nullptr, Mrows, Dm, Dm);

    // h = LN(p0 + p1 + b_o + x) -> bf16
    addn_ln<2, 0, 0><<<dim3(Mrows), dim3(256), 0, stream>>>(
        part4, x, b_o, g1, be1, nullptr, hb);

    // ff = relu(h @ w1 + b1) (bf16)
    gemm_mfma<128, 1, 0, 1><<<dim3(FFd / 128, Mrows / 128), dim3(256), 0, stream>>>(
        hb, w1T, b1, ffb, nullptr, Mrows, FFd, Dm);

    // ff2 partials = ff @ w2 (split-K 4, TN=128: 128x128 tile, 4 blocks/CU)
    gemm_mfma<128, 0, 0, 4><<<dim3(Dm / 128, Mrows / 128, 4), dim3(256), 0, stream>>>(
        ffb, w2T, nullptr, part4, nullptr, Mrows, Dm, FFd);

    // out = LN(p0 + p1 + p2 + p3 + b2 + h) -> fp32
    addn_ln<4, 1, 1><<<dim3(Mrows), dim3(256), 0, stream>>>(
        part4, hb, b2, g2, be2, out, nullptr);
}

// Round 12
// 359.487 us; speedup vs baseline: 1.0601x; 1.0262x over previous
//
#include <hip/hip_runtime.h>
#include <cstddef>
#include <cstdint>

static constexpr int Dm   = 1024;
static constexpr int Hh   = 16;
static constexpr int HDd  = 64;
static constexpr int FFd  = 4096;
static constexpr int Ls   = 2048;
static constexpr int Nb   = 2;
static constexpr int Mrows = Nb * Ls;   // 4096

typedef short bf16x8 __attribute__((ext_vector_type(8)));
typedef float f32x4  __attribute__((ext_vector_type(4)));

#if __has_builtin(__builtin_amdgcn_exp2f)
#define EXP2(x) __builtin_amdgcn_exp2f(x)
#else
#define EXP2(x) exp2f(x)
#endif

__device__ __forceinline__ ushort f2b(float f) {        // RNE (pre-pass)
    uint32_t u = __builtin_bit_cast(uint32_t, f);
    u = (u + 0x7FFFu + ((u >> 16) & 1u)) >> 16;
    return (ushort)u;
}
__device__ __forceinline__ ushort f2bf(float f) {       // fast round-half-up
    return (ushort)((__builtin_bit_cast(uint32_t, f) + 0x8000u) >> 16);
}
__device__ __forceinline__ float b2f(ushort b) {
    return __builtin_bit_cast(float, (uint32_t)b << 16);
}

__device__ __forceinline__ void gl2lds16(const ushort* g, ushort* l) {
    __builtin_amdgcn_global_load_lds(
        (const __attribute__((address_space(1))) void*)g,
        (__attribute__((address_space(3))) void*)l, 16, 0, 0);
}

// Coalesced C-store: lanes (l, l^1) exchange packed rows via shfl_xor(1);
// even lane stores rows 0,1 / odd lane rows 2,3 as dwords covering 2 cols.
template <int RELU>
__device__ __forceinline__ void pack_store_pair(
    ushort* __restrict__ C, int N, int m0, int n, int lane,
    const f32x4 a, float bv)
{
    float v0 = a[0] + bv, v1 = a[1] + bv, v2 = a[2] + bv, v3 = a[3] + bv;
    if (RELU) {
        v0 = fmaxf(v0, 0.f); v1 = fmaxf(v1, 0.f);
        v2 = fmaxf(v2, 0.f); v3 = fmaxf(v3, 0.f);
    }
    uint32_t a01 = (uint32_t)f2bf(v0) | ((uint32_t)f2bf(v1) << 16);
    uint32_t a23 = (uint32_t)f2bf(v2) | ((uint32_t)f2bf(v3) << 16);
    uint32_t x01 = (uint32_t)__shfl_xor((int)a01, 1);
    uint32_t x23 = (uint32_t)__shfl_xor((int)a23, 1);
    const bool ev = (lane & 1) == 0;
    const uint32_t low  = ev ? a01 : x23;   // value of the lower column
    const uint32_t high = ev ? x01 : a23;   // value of the higher column
    const uint32_t dA = (low & 0xFFFFu) | (high << 16);
    const uint32_t dB = (low >> 16) | (high & 0xFFFF0000u);
    const int rb = ev ? 0 : 2;
    const int nc = n - (lane & 1);
    *(uint32_t*)(C + (size_t)(m0 + rb) * N + nc)     = dA;
    *(uint32_t*)(C + (size_t)(m0 + rb + 1) * N + nc) = dB;
}

// ---------------------------------------------------------------------------
// Fused prep: convert x -> bf16 (blocks [0,4096)) and the 4 weight transposes
// (blocks [4096,16384)), dispatched by blockIdx range (block-uniform branch).
// ---------------------------------------------------------------------------
__global__ __launch_bounds__(256) void prep(
    const float* __restrict__ x, ushort* __restrict__ xb,
    const float* __restrict__ w_qkv, ushort* __restrict__ wqkvT,
    const float* __restrict__ w_o, ushort* __restrict__ woT,
    const float* __restrict__ w1, ushort* __restrict__ w1T,
    const float* __restrict__ w2, ushort* __restrict__ w2T)
{
    __shared__ float t[32][33];
    const int bid = blockIdx.x;
    const int tidx = threadIdx.x;
    if (bid < 4096) {                       // convert: 4096 x 1024 elems
        const int i = bid * 1024 + tidx * 4;
        float4 v = *(const float4*)(x + i);
        uint2 o;
        o.x = (uint32_t)f2b(v.x) | ((uint32_t)f2b(v.y) << 16);
        o.y = (uint32_t)f2b(v.z) | ((uint32_t)f2b(v.w) << 16);
        *(uint2*)(xb + i) = o;
        return;
    }
    const float* src; ushort* dst; int K, N, r;
    if (bid < 7168)       { r = bid - 4096;  src = w_qkv; dst = wqkvT; K = Dm;  N = 3 * Dm; }
    else if (bid < 8192)  { r = bid - 7168;  src = w_o;   dst = woT;   K = Dm;  N = Dm;  }
    else if (bid < 12288) { r = bid - 8192;  src = w1;    dst = w1T;   K = Dm;  N = FFd; }
    else                  { r = bid - 12288; src = w2;    dst = w2T;   K = FFd; N = Dm;  }
    const int gx = N / 32;
    const int bx = r % gx, by = r / gx;
    const int k0 = by * 32, n0 = bx * 32;
    const int tx = tidx & 31, ty = tidx >> 5;
    #pragma unroll
    for (int i = 0; i < 4; ++i)
        t[ty + i * 8][tx] = src[(size_t)(k0 + ty + i * 8) * N + n0 + tx];
    __syncthreads();
    #pragma unroll
    for (int i = 0; i < 4; ++i)
        dst[(size_t)(n0 + ty + i * 8) * K + k0 + tx] = f2b(t[tx][ty + i * 8]);
}

// ---------------------------------------------------------------------------
// bf16 MFMA GEMM, double-buffered LDS, ONE barrier per K-iter.
// C[M,N] = A[M,K] @ Bt[N,K]^T + bias. 128 x TN tile (TN=128|96|64), 256 thr.
// TN=96 (qkv): grid 1024 = 4 blocks/CU. VOUT: per-16col-fragment branch
// between Q/K pack-store and V scatter into vT[n][h][d][key].
// SPLITK>1: grid.z slices; bf16 partials at Cb + z*M*N (contiguous slots).
// ---------------------------------------------------------------------------
template <int TN, int RELU, int VOUT, int SPLITK>
__global__ __launch_bounds__(256) void gemm_mfma(
    const ushort* __restrict__ A, const ushort* __restrict__ Bt,
    const float* __restrict__ bias,
    ushort* __restrict__ Cb, ushort* __restrict__ vT, int M, int N, int K)
{
    constexpr int NT  = TN / 32;                 // B n-frags per wave
    constexpr int BSZ = TN * 32;                 // Bs shorts per buffer
    __shared__ __align__(16) ushort As[2 * 128 * 32];
    __shared__ __align__(16) ushort Bs[2 * BSZ];

    const int tid  = threadIdx.x;
    int bx, by;
    {
        const int gx = gridDim.x;
        const int nwg = gx * gridDim.y;
        const int lin = blockIdx.y * gx + blockIdx.x;
        const int swz = (lin & 7) * (nwg >> 3) + (lin >> 3);
        by = swz / gx; bx = swz - by * gx;
    }
    const int bm   = by * 128, bn = bx * TN;
    const int wave = tid >> 6, lane = tid & 63;
    const int wm = (wave & 1) * 64;
    const int wn = (wave >> 1) * (TN / 2);
    const int lr = lane & 15, lq = lane >> 4;

    const int KS   = K / SPLITK;                 // K per slice
    const int Koff = (SPLITK > 1) ? blockIdx.z * KS : 0;

    const int rr = wave * 16 + (lane >> 2);
    const int sg = lane & 3;
    const ushort* Ag = A  + (size_t)(bm + rr) * K + Koff + sg * 8;
    const ushort* Bg = Bt + (size_t)(bn + rr) * K + Koff + sg * 8;

    f32x4 acc[4][NT];
    #pragma unroll
    for (int i = 0; i < 4; ++i)
        #pragma unroll
        for (int j = 0; j < NT; ++j)
            acc[i][j] = (f32x4){0.f, 0.f, 0.f, 0.f};

    // prologue: stage k=0 into buffer 0
    gl2lds16(Ag,                  As + wave * 512);
    gl2lds16(Ag + (size_t)64 * K, As + 2048 + wave * 512);
    gl2lds16(Bg,                  Bs + wave * 512);
    if (TN == 128)
        gl2lds16(Bg + (size_t)64 * K, Bs + 2048 + wave * 512);
    if (TN == 96) {
        if (wave < 2)
            gl2lds16(Bg + (size_t)64 * K, Bs + 2048 + wave * 512);
    }

    int ib = 0;
    for (int k0 = 0; k0 < KS; k0 += 32, ib ^= 1) {
        __syncthreads();   // drains vmcnt: buffer ib is ready; buffer ib^1 free
        if (k0 + 32 < KS) {
            const int nb = ib ^ 1;
            gl2lds16(Ag + k0 + 32,                  As + nb * 4096 + wave * 512);
            gl2lds16(Ag + k0 + 32 + (size_t)64 * K, As + nb * 4096 + 2048 + wave * 512);
            gl2lds16(Bg + k0 + 32,                  Bs + nb * BSZ + wave * 512);
            if (TN == 128)
                gl2lds16(Bg + k0 + 32 + (size_t)64 * K, Bs + nb * BSZ + 2048 + wave * 512);
            if (TN == 96) {
                if (wave < 2)
                    gl2lds16(Bg + k0 + 32 + (size_t)64 * K, Bs + nb * BSZ + 2048 + wave * 512);
            }
        }

        const ushort* Ar = As + ib * 4096;
        const ushort* Br = Bs + ib * BSZ;
        bf16x8 af[4], bf[NT];
        #pragma unroll
        for (int mt = 0; mt < 4; ++mt)
            af[mt] = *(const bf16x8*)(Ar + (wm + mt * 16 + lr) * 32 + lq * 8);
        #pragma unroll
        for (int nt = 0; nt < NT; ++nt)
            bf[nt] = *(const bf16x8*)(Br + (wn + nt * 16 + lr) * 32 + lq * 8);

        #pragma unroll
        for (int mt = 0; mt < 4; ++mt)
            #pragma unroll
            for (int nt = 0; nt < NT; ++nt)
                acc[mt][nt] = __builtin_amdgcn_mfma_f32_16x16x32_bf16(
                    af[mt], bf[nt], acc[mt][nt], 0, 0, 0);
    }

    // Epilogue. C/D layout: col = lane&15, row = (lane>>4)*4 + r
    if (SPLITK > 1) {
        ushort* Cp = Cb + (size_t)blockIdx.z * M * N;
        #pragma unroll
        for (int nt = 0; nt < NT; ++nt) {
            const int n = bn + wn + nt * 16 + lr;
            #pragma unroll
            for (int mt = 0; mt < 4; ++mt)
                pack_store_pair<0>(Cp, N, bm + wm + mt * 16 + lq * 4, n, lane,
                                   acc[mt][nt], 0.0f);
        }
        return;
    }
    if (VOUT) {
        const int batch = bm >> 11;
        #pragma unroll
        for (int nt = 0; nt < NT; ++nt) {
            const int n = bn + wn + nt * 16 + lr;
            const float bv = bias[n];
            if (bn + wn + nt * 16 >= 2 * Dm) {
                // V fragment -> vT[n][h][d][key]; merge lq pairs via
                // shfl_xor(16) so each lane stores 8 contiguous keys (16B).
                const int col = n - 2 * Dm;          // 0..1023
                const int h = col >> 6, d = col & 63;
                uint2 p4[4];
                #pragma unroll
                for (int mt = 0; mt < 4; ++mt) {
                    p4[mt].x = (uint32_t)f2bf(acc[mt][nt][0] + bv) |
                               ((uint32_t)f2bf(acc[mt][nt][1] + bv) << 16);
                    p4[mt].y = (uint32_t)f2bf(acc[mt][nt][2] + bv) |
                               ((uint32_t)f2bf(acc[mt][nt][3] + bv) << 16);
                }
                uint2 q4[4];
                #pragma unroll
                for (int mt = 0; mt < 4; ++mt) {
                    q4[mt].x = (uint32_t)__shfl_xor((int)p4[mt].x, 16);
                    q4[mt].y = (uint32_t)__shfl_xor((int)p4[mt].y, 16);
                }
                ushort* drow = vT + (((size_t)(batch * Hh + h)) * HDd + d) * Ls;
                const bool evq = (lq & 1) == 0;
                #pragma unroll
                for (int t = 0; t < 2; ++t) {
                    const int mt = (evq ? 0 : 2) + t;
                    const int key = (bm + wm + mt * 16 + (lq & ~1) * 4) & (Ls - 1);
                    uint4 w;
                    if (evq) w = (uint4){p4[mt].x, p4[mt].y, q4[mt].x, q4[mt].y};
                    else     w = (uint4){q4[mt].x, q4[mt].y, p4[mt].x, p4[mt].y};
                    *(uint4*)(drow + key) = w;
                }
            } else {
                #pragma unroll
                for (int mt = 0; mt < 4; ++mt)
                    pack_store_pair<0>(Cb, N, bm + wm + mt * 16 + lq * 4, n, lane,
                                       acc[mt][nt], bv);
            }
        }
        return;
    }
    #pragma unroll
    for (int nt = 0; nt < NT; ++nt) {
        const int n = bn + wn + nt * 16 + lr;
        const float bv = bias[n];
        #pragma unroll
        for (int mt = 0; mt < 4; ++mt)
            pack_store_pair<RELU>(Cb, N, bm + wm + mt * 16 + lq * 4, n, lane,
                                  acc[mt][nt], bv);
    }
}

// ---------------------------------------------------------------------------
// MFMA flash attention, S^T formulation, no-max softmax, INTRA-BLOCK KV-split.
// 512 threads = 2 groups x 4 waves; group g covers keys [g*1024, g*1024+1024)
// for the same 128-q tile, each with its own double-staged K/V LDS buffers
// (lockstep: both groups run identical 16-iteration loops, shared barriers).
// Combine: group 1 dumps f32 O-partials + denominators into a DEDICATED
// __shared__ float buffer (round-10's reinterpret-cast overlay of live
// ushort K/V staging removed -- prime NaN suspect); group 0 sums, normalizes,
// writes bf16 out directly. Removes the npart/dpart global round-trip
// (~64 MB HBM) and the attn_combine kernel.
// P stays entirely in registers (V key-axis permuted in LDS, round 6).
// LDS: 36.9 KB staging + 34.8 KB combine = 71.7 KB -> 2 blocks/CU = grid/CU.
// ---------------------------------------------------------------------------
__global__ __launch_bounds__(512) void attn_mfma(
    const ushort* __restrict__ qkv, const ushort* __restrict__ vT,
    ushort* __restrict__ out)
{
    const int tid = threadIdx.x, wave = tid >> 6, lane = tid & 63;
    const int g = wave >> 2, wv = wave & 3;
    const int lr = lane & 15, lq = lane >> 4;
    // grid (16,16,2): swizzle (nwg=512) -> XCD c gets 64 contiguous tiles
    int bx, h, n;
    {
        const int lin = (blockIdx.z * 16 + blockIdx.y) * 16 + blockIdx.x;
        const int swz = (lin & 7) * 64 + (lin >> 3);
        bx = swz & 15; h = (swz >> 4) & 15; n = swz >> 8;
    }
    const int q0 = bx * 128 + wv * 32;
    const int kt0 = g * (Ls / 2);
    const size_t RS = 3 * Dm;
    const ushort* base  = qkv + (size_t)n * Ls * RS;
    const ushort* vbase = vT + (size_t)(n * Hh + h) * HDd * Ls;

    __shared__ __align__(16) ushort KV[4][64 * 72];   // [g*2]=K, [g*2+1]=V
    __shared__ __align__(16) float cmb[34][256];      // dedicated combine buf
    ushort* Kb = KV[2 * g];
    ushort* Vt = KV[2 * g + 1];

    // Q fragments (B-layout: n=lr=q, k=lq*8+j=d), prescaled 0.125*log2(e)
    bf16x8 qf[2][2];                                   // [ks][qh]
    {
        const float c = 0.18033688011112042f;
        #pragma unroll
        for (int qh = 0; qh < 2; ++qh) {
            const ushort* qg = base + (size_t)(q0 + qh * 16 + lr) * RS + h * HDd + lq * 8;
            bf16x8 t0 = *(const bf16x8*)(qg);
            bf16x8 t1 = *(const bf16x8*)(qg + 32);
            #pragma unroll
            for (int j = 0; j < 8; ++j) {
                qf[0][qh][j] = (short)f2b(b2f((ushort)t0[j]) * c);
                qf[1][qh][j] = (short)f2b(b2f((ushort)t1[j]) * c);
            }
        }
    }

    // all-ones A fragment for the denominator MFMA (1.0bf16 = 0x3F80)
    bf16x8 onesf;
    #pragma unroll
    for (int j = 0; j < 8; ++j) onesf[j] = (short)0x3F80;
    const f32x4 z4 = (f32x4){0.f, 0.f, 0.f, 0.f};

    f32x4 o[4][2];                                     // [dt][qh]
    #pragma unroll
    for (int dt = 0; dt < 4; ++dt)
        #pragma unroll
        for (int qh = 0; qh < 2; ++qh)
            o[dt][qh] = (f32x4){0.f, 0.f, 0.f, 0.f};
    f32x4 dacc[2];                                     // denominator acc
    dacc[0] = (f32x4){0.f, 0.f, 0.f, 0.f};
    dacc[1] = (f32x4){0.f, 0.f, 0.f, 0.f};

    const int lt = tid & 255;                          // thread within group
    const int srow = lt >> 2, ssg = lt & 3;
    const ushort* kg = base + (size_t)srow * RS + Dm + h * HDd;
    const ushort* vg = vbase + (size_t)srow * Ls;

    // V slot-permutation write bases
    const int sA = (((2 * ssg) & 3) * 8) + (((ssg >> 1) & 1) * 4);
    const int sB = (((2 * ssg + 1) & 3) * 8) + (((ssg >> 1) & 1) * 4);

    // prefetch first tile of this group's half into registers
    int4 ka = *(const int4*)(kg + (size_t)kt0 * RS + ssg * 8);
    int4 kb = *(const int4*)(kg + (size_t)kt0 * RS + (ssg + 4) * 8);
    int4 va = *(const int4*)(vg + kt0 + ssg * 8);
    int4 vb = *(const int4*)(vg + kt0 + (ssg + 4) * 8);

    for (int kt = kt0; kt < kt0 + Ls / 2; kt += 64) {
        __syncthreads();            // all reads of previous tile done
        *(int4*)(Kb + srow * 72 + ssg * 8)       = ka;
        *(int4*)(Kb + srow * 72 + (ssg + 4) * 8) = kb;
        {
            ushort* vrow = Vt + srow * 72;
            *(uint2*)(vrow + sA)      = (uint2){(uint32_t)va.x, (uint32_t)va.y};
            *(uint2*)(vrow + sB)      = (uint2){(uint32_t)va.z, (uint32_t)va.w};
            *(uint2*)(vrow + 32 + sA) = (uint2){(uint32_t)vb.x, (uint32_t)vb.y};
            *(uint2*)(vrow + 32 + sB) = (uint2){(uint32_t)vb.z, (uint32_t)vb.w};
        }
        __syncthreads();

        // T14: issue next tile's global loads; latency hides under compute
        if (kt + 64 < kt0 + Ls / 2) {
            const ushort* kp = kg + (size_t)(kt + 64) * RS;
            const ushort* vp = vg + (kt + 64);
            ka = *(const int4*)(kp + ssg * 8);
            kb = *(const int4*)(kp + (ssg + 4) * 8);
            va = *(const int4*)(vp + ssg * 8);
            vb = *(const int4*)(vp + (ssg + 4) * 8);
        }

        // S^T = K Q^T : [64 key][32 q], exp2 domain
        f32x4 s[4][2];
        #pragma unroll
        for (int ks = 0; ks < 2; ++ks)
            #pragma unroll
            for (int mt = 0; mt < 4; ++mt) {
                bf16x8 kf = *(const bf16x8*)(Kb + (mt * 16 + lr) * 72 + ks * 32 + lq * 8);
                #pragma unroll
                for (int qh = 0; qh < 2; ++qh)
                    s[mt][qh] = __builtin_amdgcn_mfma_f32_16x16x32_bf16(
                        kf, qf[ks][qh], ks == 0 ? z4 : s[mt][qh], 0, 0, 0);
            }

        // p = exp2(s), pack bf16 pairs with v_cvt_pk_bf16_f32
        uint2 pb[4][2];
        #pragma unroll
        for (int mt = 0; mt < 4; ++mt)
            #pragma unroll
            for (int qh = 0; qh < 2; ++qh) {
                float p0 = EXP2(s[mt][qh][0]);
                float p1 = EXP2(s[mt][qh][1]);
                float p2 = EXP2(s[mt][qh][2]);
                float p3 = EXP2(s[mt][qh][3]);
                uint32_t w0, w1;
                asm("v_cvt_pk_bf16_f32 %0, %1, %2" : "=v"(w0) : "v"(p0), "v"(p1));
                asm("v_cvt_pk_bf16_f32 %0, %1, %2" : "=v"(w1) : "v"(p2), "v"(p3));
                pb[mt][qh].x = w0;
                pb[mt][qh].y = w1;
            }

        // O^T += V^T P^T over permuted slots; P fragment = register concat.
        #pragma unroll
        for (int ks = 0; ks < 2; ++ks) {
            bf16x8 pf[2];
            #pragma unroll
            for (int qh = 0; qh < 2; ++qh) {
                uint4 u = (uint4){pb[2 * ks][qh].x, pb[2 * ks][qh].y,
                                  pb[2 * ks + 1][qh].x, pb[2 * ks + 1][qh].y};
                pf[qh] = __builtin_bit_cast(bf16x8, u);
            }
            #pragma unroll
            for (int dt = 0; dt < 4; ++dt) {
                bf16x8 vf = *(const bf16x8*)(Vt + (dt * 16 + lr) * 72 + ks * 32 + lq * 8);
                #pragma unroll
                for (int qh = 0; qh < 2; ++qh)
                    o[dt][qh] = __builtin_amdgcn_mfma_f32_16x16x32_bf16(
                        vf, pf[qh], o[dt][qh], 0, 0, 0);
            }
            #pragma unroll
            for (int qh = 0; qh < 2; ++qh)
                dacc[qh] = __builtin_amdgcn_mfma_f32_16x16x32_bf16(
                    onesf, pf[qh], dacc[qh], 0, 0, 0);
        }
    }

    // Cross-group combine through the dedicated cmb buffer. Thread (g,wv,lane)
    // in both groups owns the same (q = q0+qh*16+lr, d = dt*16+lq*4+r) set,
    // so a flat per-group thread index c pairs them exactly.
    const int c = wv * 64 + lane;
    __syncthreads();                    // group-1 compute done before dump
    if (g == 1) {
        #pragma unroll
        for (int dt = 0; dt < 4; ++dt)
            #pragma unroll
            for (int qh = 0; qh < 2; ++qh)
                #pragma unroll
                for (int r = 0; r < 4; ++r)
                    cmb[dt * 8 + qh * 4 + r][c] = o[dt][qh][r];
        cmb[32][c] = dacc[0][0];
        cmb[33][c] = dacc[1][0];
    }
    __syncthreads();
    if (g == 0) {
        #pragma unroll
        for (int dt = 0; dt < 4; ++dt)
            #pragma unroll
            for (int qh = 0; qh < 2; ++qh)
                #pragma unroll
                for (int r = 0; r < 4; ++r)
                    o[dt][qh][r] += cmb[dt * 8 + qh * 4 + r][c];
        const float d0 = dacc[0][0] + cmb[32][c];
        const float d1 = dacc[1][0] + cmb[33][c];
        #pragma unroll
        for (int qh = 0; qh < 2; ++qh) {
            const float inv = 1.0f / (qh == 0 ? d0 : d1);
            ushort* orow = out + (size_t)(n * Ls + q0 + qh * 16 + lr) * Dm + h * HDd;
            #pragma unroll
            for (int dt = 0; dt < 4; ++dt) {
                ushort4 ob;
                ushort* op = (ushort*)&ob;
                #pragma unroll
                for (int r = 0; r < 4; ++r) op[r] = f2bf(o[dt][qh][r] * inv);
                *(ushort4*)(orow + dt * 16 + lq * 4) = ob;
            }
        }
    }
}

// ---------------------------------------------------------------------------
// out = LayerNorm(sum_{p<NP} part[p] + bias + other) * gamma + beta.
// part slots are contiguous 8MB bf16 buffers at part + p*Mrows*Dm.
// ---------------------------------------------------------------------------
template <int NP, int OTHER_BF16, int OUT_F32>
__global__ __launch_bounds__(256) void addn_ln(
    const ushort* __restrict__ part, const void* __restrict__ other,
    const float* __restrict__ bias,
    const float* __restrict__ gamma, const float* __restrict__ beta,
    float* __restrict__ outf, ushort* __restrict__ outb)
{
    const int row = blockIdx.x;
    const int tid = threadIdx.x;

    float4 bv = ((const float4*)bias)[tid];
    float v[4];
    if (OTHER_BF16) {
        ushort4 u = ((const ushort4*)((const ushort*)other + (size_t)row * Dm))[tid];
        v[0] = b2f(u.x) + bv.x; v[1] = b2f(u.y) + bv.y;
        v[2] = b2f(u.z) + bv.z; v[3] = b2f(u.w) + bv.w;
    } else {
        float4 f = ((const float4*)((const float*)other + (size_t)row * Dm))[tid];
        v[0] = f.x + bv.x; v[1] = f.y + bv.y; v[2] = f.z + bv.z; v[3] = f.w + bv.w;
    }
    #pragma unroll
    for (int pp = 0; pp < NP; ++pp) {
        ushort4 u = ((const ushort4*)(part + (size_t)pp * Mrows * Dm
                                           + (size_t)row * Dm))[tid];
        v[0] += b2f(u.x); v[1] += b2f(u.y); v[2] += b2f(u.z); v[3] += b2f(u.w);
    }

    float s  = v[0] + v[1] + v[2] + v[3];
    float sq = v[0]*v[0] + v[1]*v[1] + v[2]*v[2] + v[3]*v[3];

    __shared__ float red[8];
    #pragma unroll
    for (int off = 32; off > 0; off >>= 1) {
        s  += __shfl_down(s, off);
        sq += __shfl_down(sq, off);
    }
    const int wv = tid >> 6;
    if ((tid & 63) == 0) { red[wv] = s; red[4 + wv] = sq; }
    __syncthreads();
    s  = red[0] + red[1] + red[2] + red[3];
    sq = red[4] + red[5] + red[6] + red[7];

    const float mu  = s * (1.0f / Dm);
    const float var = sq * (1.0f / Dm) - mu * mu;
    const float inv = rsqrtf(var + 1e-5f);

    const float4 g  = ((const float4*)gamma)[tid];
    const float4 be = ((const float4*)beta)[tid];
    float ov[4];
    ov[0] = (v[0] - mu) * inv * g.x + be.x;
    ov[1] = (v[1] - mu) * inv * g.y + be.y;
    ov[2] = (v[2] - mu) * inv * g.z + be.z;
    ov[3] = (v[3] - mu) * inv * g.w + be.w;
    if (OUT_F32) {
        float4 o4 = {ov[0], ov[1], ov[2], ov[3]};
        ((float4*)(outf + (size_t)row * Dm))[tid] = o4;
    } else {
        uint2 ob;
        ob.x = (uint32_t)f2bf(ov[0]) | ((uint32_t)f2bf(ov[1]) << 16);
        ob.y = (uint32_t)f2bf(ov[2]) | ((uint32_t)f2bf(ov[3]) << 16);
        *(uint2*)(outb + (size_t)row * Dm + tid * 4) = ob;
    }
}

// ---------------------------------------------------------------------------
extern "C" void kernel_launch(void* const* d_in, const int* in_sizes, int n_in,
                              void* d_out, int out_size, void* d_ws, size_t ws_size,
                              hipStream_t stream)
{
    const float* x     = (const float*)d_in[0];
    const float* w_qkv = (const float*)d_in[1];
    const float* b_qkv = (const float*)d_in[2];
    const float* w_o   = (const float*)d_in[3];
    const float* b_o   = (const float*)d_in[4];
    const float* g1    = (const float*)d_in[5];
    const float* be1   = (const float*)d_in[6];
    const float* w1    = (const float*)d_in[7];
    const float* b1    = (const float*)d_in[8];
    const float* w2    = (const float*)d_in[9];
    const float* b2    = (const float*)d_in[10];
    const float* g2    = (const float*)d_in[11];
    const float* be2   = (const float*)d_in[12];
    float* out = (float*)d_out;

    // Workspace. part4 = 4 contiguous 8MB bf16 partial slots:
    //   slots 0,1: proj / ff2 split-K partials
    //   slot 2:    attnb  (dead once proj consumed it -> ff2 partial z=2)
    //   slot 3:    xb     (dead once qkv consumed it  -> ff2 partial z=3)
    char* p = (char*)d_ws;
    ushort* part4 = (ushort*)p;  p += (size_t)4 * Mrows * Dm * 2;   // 32 MB
    ushort* qkvb  = (ushort*)p;  p += (size_t)Mrows * 3 * Dm * 2;
    ushort* hb    = (ushort*)p;  p += (size_t)Mrows * Dm * 2;
    ushort* ffb   = (ushort*)p;  p += (size_t)Mrows * FFd * 2;
    ushort* wqkvT = (ushort*)p;  p += (size_t)(3 * Dm) * Dm * 2;
    ushort* woT   = (ushort*)p;  p += (size_t)Dm * Dm * 2;
    ushort* w1T   = (ushort*)p;  p += (size_t)FFd * Dm * 2;
    ushort* w2T   = (ushort*)p;  p += (size_t)Dm * FFd * 2;
    ushort* vTg   = (ushort*)p;  p += (size_t)Mrows * Dm * 2;

    ushort* attnb = part4 + (size_t)2 * Mrows * Dm;
    ushort* xb    = part4 + (size_t)3 * Mrows * Dm;

    // fused convert + weight transposes (1 launch instead of 5)
    prep<<<dim3(16384), dim3(256), 0, stream>>>(
        x, xb, w_qkv, wqkvT, w_o, woT, w1, w1T, w2, w2T);

    // qkv = x @ w_qkv + b_qkv; TN=96 -> 4 blocks/CU. Q,K -> qkvb, V -> vTg.
    gemm_mfma<96, 0, 1, 1><<<dim3(3 * Dm / 96, Mrows / 128), dim3(256), 0, stream>>>(
        xb, wqkvT, b_qkv, qkvb, vTg, Mrows, 3 * Dm, Dm);

    // attn: intra-block KV-split, direct bf16 output (no combine kernel)
    attn_mfma<<<dim3(Ls / 128, Hh, Nb), dim3(512), 0, stream>>>(qkvb, vTg, attnb);

    // proj partials = attn @ w_o (split-K 2 -> slots 0,1)
    gemm_mfma<64, 0, 0, 2><<<dim3(Dm / 64, Mrows / 128, 2), dim3(256), 0, stream>>>(
        attnb, woT, nullptr, part4, nullptr, Mrows, Dm, Dm);

    // h = LN(p0 + p1 + b_o + x) -> bf16
    addn_ln<2, 0, 0><<<dim3(Mrows), dim3(256), 0, stream>>>(
        part4, x, b_o, g1, be1, nullptr, hb);

    // ff = relu(h @ w1 + b1) (bf16)
    gemm_mfma<128, 1, 0, 1><<<dim3(FFd / 128, Mrows / 128), dim3(256), 0, stream>>>(
        hb, w1T, b1, ffb, nullptr, Mrows, FFd, Dm);

    // ff2 partials = ff @ w2 (split-K 4, TN=128: 128x128 tile, 4 blocks/CU)
    gemm_mfma<128, 0, 0, 4><<<dim3(Dm / 128, Mrows / 128, 4), dim3(256), 0, stream>>>(
        ffb, w2T, nullptr, part4, nullptr, Mrows, Dm, FFd);

    // out = LN(p0 + p1 + p2 + p3 + b2 + h) -> fp32
    addn_ln<4, 1, 1><<<dim3(Mrows), dim3(256), 0, stream>>>(
        part4, hb, b2, g2, be2, out, nullptr);
}

// Round 13
// 355.463 us; speedup vs baseline: 1.0721x; 1.0113x over previous
//
#include <hip/hip_runtime.h>
#include <cstddef>
#include <cstdint>

static constexpr int Dm   = 1024;
static constexpr int Hh   = 16;
static constexpr int HDd  = 64;
static constexpr int FFd  = 4096;
static constexpr int Ls   = 2048;
static constexpr int Nb   = 2;
static constexpr int Mrows = Nb * Ls;   // 4096

typedef short bf16x8 __attribute__((ext_vector_type(8)));
typedef float f32x4  __attribute__((ext_vector_type(4)));

#if __has_builtin(__builtin_amdgcn_exp2f)
#define EXP2(x) __builtin_amdgcn_exp2f(x)
#else
#define EXP2(x) exp2f(x)
#endif

__device__ __forceinline__ ushort f2b(float f) {        // RNE (pre-pass)
    uint32_t u = __builtin_bit_cast(uint32_t, f);
    u = (u + 0x7FFFu + ((u >> 16) & 1u)) >> 16;
    return (ushort)u;
}
__device__ __forceinline__ ushort f2bf(float f) {       // fast round-half-up
    return (ushort)((__builtin_bit_cast(uint32_t, f) + 0x8000u) >> 16);
}
__device__ __forceinline__ float b2f(ushort b) {
    return __builtin_bit_cast(float, (uint32_t)b << 16);
}

__device__ __forceinline__ void gl2lds16(const ushort* g, ushort* l) {
    __builtin_amdgcn_global_load_lds(
        (const __attribute__((address_space(1))) void*)g,
        (__attribute__((address_space(3))) void*)l, 16, 0, 0);
}

// Coalesced C-store: lanes (l, l^1) exchange packed rows via shfl_xor(1);
// even lane stores rows 0,1 / odd lane rows 2,3 as dwords covering 2 cols.
template <int RELU>
__device__ __forceinline__ void pack_store_pair(
    ushort* __restrict__ C, int N, int m0, int n, int lane,
    const f32x4 a, float bv)
{
    float v0 = a[0] + bv, v1 = a[1] + bv, v2 = a[2] + bv, v3 = a[3] + bv;
    if (RELU) {
        v0 = fmaxf(v0, 0.f); v1 = fmaxf(v1, 0.f);
        v2 = fmaxf(v2, 0.f); v3 = fmaxf(v3, 0.f);
    }
    uint32_t a01 = (uint32_t)f2bf(v0) | ((uint32_t)f2bf(v1) << 16);
    uint32_t a23 = (uint32_t)f2bf(v2) | ((uint32_t)f2bf(v3) << 16);
    uint32_t x01 = (uint32_t)__shfl_xor((int)a01, 1);
    uint32_t x23 = (uint32_t)__shfl_xor((int)a23, 1);
    const bool ev = (lane & 1) == 0;
    const uint32_t low  = ev ? a01 : x23;   // value of the lower column
    const uint32_t high = ev ? x01 : a23;   // value of the higher column
    const uint32_t dA = (low & 0xFFFFu) | (high << 16);
    const uint32_t dB = (low >> 16) | (high & 0xFFFF0000u);
    const int rb = ev ? 0 : 2;
    const int nc = n - (lane & 1);
    *(uint32_t*)(C + (size_t)(m0 + rb) * N + nc)     = dA;
    *(uint32_t*)(C + (size_t)(m0 + rb + 1) * N + nc) = dB;
}

// ---------------------------------------------------------------------------
// Fused prep: convert x -> bf16 (blocks [0,4096)) and the 4 weight transposes
// (blocks [4096,16384)), dispatched by blockIdx range (block-uniform branch).
// ---------------------------------------------------------------------------
__global__ __launch_bounds__(256) void prep(
    const float* __restrict__ x, ushort* __restrict__ xb,
    const float* __restrict__ w_qkv, ushort* __restrict__ wqkvT,
    const float* __restrict__ w_o, ushort* __restrict__ woT,
    const float* __restrict__ w1, ushort* __restrict__ w1T,
    const float* __restrict__ w2, ushort* __restrict__ w2T)
{
    __shared__ float t[32][33];
    const int bid = blockIdx.x;
    const int tidx = threadIdx.x;
    if (bid < 4096) {                       // convert: 4096 x 1024 elems
        const int i = bid * 1024 + tidx * 4;
        float4 v = *(const float4*)(x + i);
        uint2 o;
        o.x = (uint32_t)f2b(v.x) | ((uint32_t)f2b(v.y) << 16);
        o.y = (uint32_t)f2b(v.z) | ((uint32_t)f2b(v.w) << 16);
        *(uint2*)(xb + i) = o;
        return;
    }
    const float* src; ushort* dst; int K, N, r;
    if (bid < 7168)       { r = bid - 4096;  src = w_qkv; dst = wqkvT; K = Dm;  N = 3 * Dm; }
    else if (bid < 8192)  { r = bid - 7168;  src = w_o;   dst = woT;   K = Dm;  N = Dm;  }
    else if (bid < 12288) { r = bid - 8192;  src = w1;    dst = w1T;   K = Dm;  N = FFd; }
    else                  { r = bid - 12288; src = w2;    dst = w2T;   K = FFd; N = Dm;  }
    const int gx = N / 32;
    const int bx = r % gx, by = r / gx;
    const int k0 = by * 32, n0 = bx * 32;
    const int tx = tidx & 31, ty = tidx >> 5;
    #pragma unroll
    for (int i = 0; i < 4; ++i)
        t[ty + i * 8][tx] = src[(size_t)(k0 + ty + i * 8) * N + n0 + tx];
    __syncthreads();
    #pragma unroll
    for (int i = 0; i < 4; ++i)
        dst[(size_t)(n0 + ty + i * 8) * K + k0 + tx] = f2b(t[tx][ty + i * 8]);
}

// ---------------------------------------------------------------------------
// bf16 MFMA GEMM, double-buffered LDS, ONE barrier per K-iter (2-phase).
// Used for qkv (TN=96, VOUT) and proj (TN=64, SPLITK=2).
// ---------------------------------------------------------------------------
template <int TN, int RELU, int VOUT, int SPLITK>
__global__ __launch_bounds__(256) void gemm_mfma(
    const ushort* __restrict__ A, const ushort* __restrict__ Bt,
    const float* __restrict__ bias,
    ushort* __restrict__ Cb, ushort* __restrict__ vT, int M, int N, int K)
{
    constexpr int NT  = TN / 32;                 // B n-frags per wave
    constexpr int BSZ = TN * 32;                 // Bs shorts per buffer
    __shared__ __align__(16) ushort As[2 * 128 * 32];
    __shared__ __align__(16) ushort Bs[2 * BSZ];

    const int tid  = threadIdx.x;
    int bx, by;
    {
        const int gx = gridDim.x;
        const int nwg = gx * gridDim.y;
        const int lin = blockIdx.y * gx + blockIdx.x;
        const int swz = (lin & 7) * (nwg >> 3) + (lin >> 3);
        by = swz / gx; bx = swz - by * gx;
    }
    const int bm   = by * 128, bn = bx * TN;
    const int wave = tid >> 6, lane = tid & 63;
    const int wm = (wave & 1) * 64;
    const int wn = (wave >> 1) * (TN / 2);
    const int lr = lane & 15, lq = lane >> 4;

    const int KS   = K / SPLITK;                 // K per slice
    const int Koff = (SPLITK > 1) ? blockIdx.z * KS : 0;

    const int rr = wave * 16 + (lane >> 2);
    const int sg = lane & 3;
    const ushort* Ag = A  + (size_t)(bm + rr) * K + Koff + sg * 8;
    const ushort* Bg = Bt + (size_t)(bn + rr) * K + Koff + sg * 8;

    f32x4 acc[4][NT];
    #pragma unroll
    for (int i = 0; i < 4; ++i)
        #pragma unroll
        for (int j = 0; j < NT; ++j)
            acc[i][j] = (f32x4){0.f, 0.f, 0.f, 0.f};

    // prologue: stage k=0 into buffer 0
    gl2lds16(Ag,                  As + wave * 512);
    gl2lds16(Ag + (size_t)64 * K, As + 2048 + wave * 512);
    gl2lds16(Bg,                  Bs + wave * 512);
    if (TN == 128)
        gl2lds16(Bg + (size_t)64 * K, Bs + 2048 + wave * 512);
    if (TN == 96) {
        if (wave < 2)
            gl2lds16(Bg + (size_t)64 * K, Bs + 2048 + wave * 512);
    }

    int ib = 0;
    for (int k0 = 0; k0 < KS; k0 += 32, ib ^= 1) {
        __syncthreads();   // drains vmcnt: buffer ib is ready; buffer ib^1 free
        if (k0 + 32 < KS) {
            const int nb = ib ^ 1;
            gl2lds16(Ag + k0 + 32,                  As + nb * 4096 + wave * 512);
            gl2lds16(Ag + k0 + 32 + (size_t)64 * K, As + nb * 4096 + 2048 + wave * 512);
            gl2lds16(Bg + k0 + 32,                  Bs + nb * BSZ + wave * 512);
            if (TN == 128)
                gl2lds16(Bg + k0 + 32 + (size_t)64 * K, Bs + nb * BSZ + 2048 + wave * 512);
            if (TN == 96) {
                if (wave < 2)
                    gl2lds16(Bg + k0 + 32 + (size_t)64 * K, Bs + nb * BSZ + 2048 + wave * 512);
            }
        }

        const ushort* Ar = As + ib * 4096;
        const ushort* Br = Bs + ib * BSZ;
        bf16x8 af[4], bf[NT];
        #pragma unroll
        for (int mt = 0; mt < 4; ++mt)
            af[mt] = *(const bf16x8*)(Ar + (wm + mt * 16 + lr) * 32 + lq * 8);
        #pragma unroll
        for (int nt = 0; nt < NT; ++nt)
            bf[nt] = *(const bf16x8*)(Br + (wn + nt * 16 + lr) * 32 + lq * 8);

        #pragma unroll
        for (int mt = 0; mt < 4; ++mt)
            #pragma unroll
            for (int nt = 0; nt < NT; ++nt)
                acc[mt][nt] = __builtin_amdgcn_mfma_f32_16x16x32_bf16(
                    af[mt], bf[nt], acc[mt][nt], 0, 0, 0);
    }

    // Epilogue. C/D layout: col = lane&15, row = (lane>>4)*4 + r
    if (SPLITK > 1) {
        ushort* Cp = Cb + (size_t)blockIdx.z * M * N;
        #pragma unroll
        for (int nt = 0; nt < NT; ++nt) {
            const int n = bn + wn + nt * 16 + lr;
            #pragma unroll
            for (int mt = 0; mt < 4; ++mt)
                pack_store_pair<0>(Cp, N, bm + wm + mt * 16 + lq * 4, n, lane,
                                   acc[mt][nt], 0.0f);
        }
        return;
    }
    if (VOUT) {
        const int batch = bm >> 11;
        #pragma unroll
        for (int nt = 0; nt < NT; ++nt) {
            const int n = bn + wn + nt * 16 + lr;
            const float bv = bias[n];
            if (bn + wn + nt * 16 >= 2 * Dm) {
                // V fragment -> vT[n][h][d][key]; merge lq pairs via
                // shfl_xor(16) so each lane stores 8 contiguous keys (16B).
                const int col = n - 2 * Dm;          // 0..1023
                const int h = col >> 6, d = col & 63;
                uint2 p4[4];
                #pragma unroll
                for (int mt = 0; mt < 4; ++mt) {
                    p4[mt].x = (uint32_t)f2bf(acc[mt][nt][0] + bv) |
                               ((uint32_t)f2bf(acc[mt][nt][1] + bv) << 16);
                    p4[mt].y = (uint32_t)f2bf(acc[mt][nt][2] + bv) |
                               ((uint32_t)f2bf(acc[mt][nt][3] + bv) << 16);
                }
                uint2 q4[4];
                #pragma unroll
                for (int mt = 0; mt < 4; ++mt) {
                    q4[mt].x = (uint32_t)__shfl_xor((int)p4[mt].x, 16);
                    q4[mt].y = (uint32_t)__shfl_xor((int)p4[mt].y, 16);
                }
                ushort* drow = vT + (((size_t)(batch * Hh + h)) * HDd + d) * Ls;
                const bool evq = (lq & 1) == 0;
                #pragma unroll
                for (int t = 0; t < 2; ++t) {
                    const int mt = (evq ? 0 : 2) + t;
                    const int key = (bm + wm + mt * 16 + (lq & ~1) * 4) & (Ls - 1);
                    uint4 w;
                    if (evq) w = (uint4){p4[mt].x, p4[mt].y, q4[mt].x, q4[mt].y};
                    else     w = (uint4){q4[mt].x, q4[mt].y, p4[mt].x, p4[mt].y};
                    *(uint4*)(drow + key) = w;
                }
            } else {
                #pragma unroll
                for (int mt = 0; mt < 4; ++mt)
                    pack_store_pair<0>(Cb, N, bm + wm + mt * 16 + lq * 4, n, lane,
                                       acc[mt][nt], bv);
            }
        }
        return;
    }
    #pragma unroll
    for (int nt = 0; nt < NT; ++nt) {
        const int n = bn + wn + nt * 16 + lr;
        const float bv = bias[n];
        #pragma unroll
        for (int mt = 0; mt < 4; ++mt)
            pack_store_pair<RELU>(Cb, N, bm + wm + mt * 16 + lq * 4, n, lane,
                                  acc[mt][nt], bv);
    }
}

// ---------------------------------------------------------------------------
// gemm256: 256x256-tile phase-split GEMM (T2+T3+T4+T5), for ff and ff2.
// 512 thr = 8 waves (2M x 4N), per-wave 128x64 out. BK=32, 3-deep LDS
// pipeline (3 x 32 KB): stage tile t+2 while computing t; per-iter wait is
// counted s_waitcnt vmcnt(4) (the 4 newest gload_lds = t+2 prefetch stay in
// flight) + raw s_barrier — never vmcnt(0) in the main loop. Exactly 4
// gload_lds per thread per tile keeps the count exact; no other VMEM in loop.
// LDS XOR-swizzle: chunk (row,cb) holds global cb ^ f(row),
// f(row) = (row ^ (row>>2)) & 3; reads apply the same involution ->
// 2 lanes/bank (free). Source-side pre-swizzle (gload_lds writes linearly).
// 4 phases/iter (one C-quadrant, 8 MFMA) with setprio around MFMA cluster.
// ---------------------------------------------------------------------------
template <int RELU, int SPLITK>
__global__ __launch_bounds__(512, 2) void gemm256(
    const ushort* __restrict__ A, const ushort* __restrict__ Bt,
    const float* __restrict__ bias, ushort* __restrict__ Cb,
    int M, int N, int K)
{
    __shared__ __align__(16) ushort As3[3][256 * 32];
    __shared__ __align__(16) ushort Bs3[3][256 * 32];

    const int tid = threadIdx.x, wave = tid >> 6, lane = tid & 63;
    const int lr = lane & 15, lq = lane >> 4;
    const int wm2 = wave >> 2, wn2 = wave & 3;

    int bx, by;
    {
        const int gx = gridDim.x;
        const int nwg = gx * gridDim.y;
        const int lin = blockIdx.y * gx + blockIdx.x;
        const int swz = (lin & 7) * (nwg >> 3) + (lin >> 3);
        by = swz / gx; bx = swz - by * gx;
    }
    const int bm = by * 256, bn = bx * 256;
    const int KS = K / SPLITK;
    const int Koff = (SPLITK > 1) ? blockIdx.z * KS : 0;
    const int nt = KS / 32;

    // staging map: chunk c = (wave*2+j)*64 + lane -> row = c>>2, cb = c&3;
    // source col-block pre-swizzled: cbS = cb ^ f(row).
    int srow[2], scbS[2];
    #pragma unroll
    for (int j = 0; j < 2; ++j) {
        const int c = (wave * 2 + j) * 64 + lane;
        const int row = c >> 2, cb = c & 3;
        srow[j] = row;
        scbS[j] = cb ^ ((row ^ (row >> 2)) & 3);
    }

    f32x4 acc[8][4];
    #pragma unroll
    for (int i = 0; i < 8; ++i)
        #pragma unroll
        for (int j = 0; j < 4; ++j)
            acc[i][j] = (f32x4){0.f, 0.f, 0.f, 0.f};

    #define STAGE(t)                                                          \
        do {                                                                  \
            const int b_ = (t) % 3;                                           \
            _Pragma("unroll")                                                 \
            for (int j_ = 0; j_ < 2; ++j_) {                                  \
                gl2lds16(A + (size_t)(bm + srow[j_]) * K + Koff + (t) * 32    \
                           + scbS[j_] * 8,                                    \
                         As3[b_] + (wave * 2 + j_) * 512);                    \
                gl2lds16(Bt + (size_t)(bn + srow[j_]) * K + Koff + (t) * 32   \
                           + scbS[j_] * 8,                                    \
                         Bs3[b_] + (wave * 2 + j_) * 512);                    \
            }                                                                 \
        } while (0)

    STAGE(0);
    STAGE(1);          // 8 outstanding per thread

    for (int t = 0; t < nt; ++t) {
        // ensure tile t landed: all but the 4 newest loads (t+2 prefetch,
        // or t+1 on the penultimate iter) drained. Final iter drains fully.
        if (t + 1 < nt) asm volatile("s_waitcnt vmcnt(4)" ::: "memory");
        else            asm volatile("s_waitcnt vmcnt(0)" ::: "memory");
        asm volatile("s_barrier" ::: "memory");
        if (t + 2 < nt) STAGE(t + 2);    // overwrites buf[(t-1)%3]: reads done

        const ushort* Ar = As3[t % 3];
        const ushort* Br = Bs3[t % 3];
        #pragma unroll
        for (int q = 0; q < 4; ++q) {
            const int qm = q >> 1, qn = q & 1;
            bf16x8 af[4], bf[2];
            #pragma unroll
            for (int i = 0; i < 4; ++i) {
                const int r = wm2 * 128 + (qm * 4 + i) * 16 + lr;
                af[i] = *(const bf16x8*)(Ar + r * 32
                            + (lq ^ ((r ^ (r >> 2)) & 3)) * 8);
            }
            #pragma unroll
            for (int i = 0; i < 2; ++i) {
                const int r = wn2 * 64 + (qn * 2 + i) * 16 + lr;
                bf[i] = *(const bf16x8*)(Br + r * 32
                            + (lq ^ ((r ^ (r >> 2)) & 3)) * 8);
            }
            __builtin_amdgcn_s_setprio(1);
            #pragma unroll
            for (int i = 0; i < 4; ++i)
                #pragma unroll
                for (int k2 = 0; k2 < 2; ++k2)
                    acc[qm * 4 + i][qn * 2 + k2] =
                        __builtin_amdgcn_mfma_f32_16x16x32_bf16(
                            af[i], bf[k2], acc[qm * 4 + i][qn * 2 + k2], 0, 0, 0);
            __builtin_amdgcn_s_setprio(0);
        }
    }
    #undef STAGE

    // Epilogue. col = lane&15 -> n, row = lq*4 + r -> m.
    if (SPLITK > 1) {
        ushort* Cp = Cb + (size_t)blockIdx.z * M * N;
        #pragma unroll
        for (int mi = 0; mi < 8; ++mi) {
            const int m0 = bm + wm2 * 128 + mi * 16 + lq * 4;
            #pragma unroll
            for (int ni = 0; ni < 4; ++ni) {
                const int n = bn + wn2 * 64 + ni * 16 + lr;
                pack_store_pair<0>(Cp, N, m0, n, lane, acc[mi][ni], 0.0f);
            }
        }
        return;
    }
    #pragma unroll
    for (int mi = 0; mi < 8; ++mi) {
        const int m0 = bm + wm2 * 128 + mi * 16 + lq * 4;
        #pragma unroll
        for (int ni = 0; ni < 4; ++ni) {
            const int n = bn + wn2 * 64 + ni * 16 + lr;
            pack_store_pair<RELU>(Cb, N, m0, n, lane, acc[mi][ni], bias[n]);
        }
    }
}

// ---------------------------------------------------------------------------
// MFMA flash attention, S^T formulation, no-max softmax, INTRA-BLOCK KV-split.
// (unchanged from round 12)
// ---------------------------------------------------------------------------
__global__ __launch_bounds__(512) void attn_mfma(
    const ushort* __restrict__ qkv, const ushort* __restrict__ vT,
    ushort* __restrict__ out)
{
    const int tid = threadIdx.x, wave = tid >> 6, lane = tid & 63;
    const int g = wave >> 2, wv = wave & 3;
    const int lr = lane & 15, lq = lane >> 4;
    int bx, h, n;
    {
        const int lin = (blockIdx.z * 16 + blockIdx.y) * 16 + blockIdx.x;
        const int swz = (lin & 7) * 64 + (lin >> 3);
        bx = swz & 15; h = (swz >> 4) & 15; n = swz >> 8;
    }
    const int q0 = bx * 128 + wv * 32;
    const int kt0 = g * (Ls / 2);
    const size_t RS = 3 * Dm;
    const ushort* base  = qkv + (size_t)n * Ls * RS;
    const ushort* vbase = vT + (size_t)(n * Hh + h) * HDd * Ls;

    __shared__ __align__(16) ushort KV[4][64 * 72];   // [g*2]=K, [g*2+1]=V
    __shared__ __align__(16) float cmb[34][256];      // dedicated combine buf
    ushort* Kb = KV[2 * g];
    ushort* Vt = KV[2 * g + 1];

    bf16x8 qf[2][2];                                   // [ks][qh]
    {
        const float c = 0.18033688011112042f;
        #pragma unroll
        for (int qh = 0; qh < 2; ++qh) {
            const ushort* qg = base + (size_t)(q0 + qh * 16 + lr) * RS + h * HDd + lq * 8;
            bf16x8 t0 = *(const bf16x8*)(qg);
            bf16x8 t1 = *(const bf16x8*)(qg + 32);
            #pragma unroll
            for (int j = 0; j < 8; ++j) {
                qf[0][qh][j] = (short)f2b(b2f((ushort)t0[j]) * c);
                qf[1][qh][j] = (short)f2b(b2f((ushort)t1[j]) * c);
            }
        }
    }

    bf16x8 onesf;
    #pragma unroll
    for (int j = 0; j < 8; ++j) onesf[j] = (short)0x3F80;
    const f32x4 z4 = (f32x4){0.f, 0.f, 0.f, 0.f};

    f32x4 o[4][2];
    #pragma unroll
    for (int dt = 0; dt < 4; ++dt)
        #pragma unroll
        for (int qh = 0; qh < 2; ++qh)
            o[dt][qh] = (f32x4){0.f, 0.f, 0.f, 0.f};
    f32x4 dacc[2];
    dacc[0] = (f32x4){0.f, 0.f, 0.f, 0.f};
    dacc[1] = (f32x4){0.f, 0.f, 0.f, 0.f};

    const int lt = tid & 255;
    const int srow = lt >> 2, ssg = lt & 3;
    const ushort* kg = base + (size_t)srow * RS + Dm + h * HDd;
    const ushort* vg = vbase + (size_t)srow * Ls;

    const int sA = (((2 * ssg) & 3) * 8) + (((ssg >> 1) & 1) * 4);
    const int sB = (((2 * ssg + 1) & 3) * 8) + (((ssg >> 1) & 1) * 4);

    int4 ka = *(const int4*)(kg + (size_t)kt0 * RS + ssg * 8);
    int4 kb = *(const int4*)(kg + (size_t)kt0 * RS + (ssg + 4) * 8);
    int4 va = *(const int4*)(vg + kt0 + ssg * 8);
    int4 vb = *(const int4*)(vg + kt0 + (ssg + 4) * 8);

    for (int kt = kt0; kt < kt0 + Ls / 2; kt += 64) {
        __syncthreads();
        *(int4*)(Kb + srow * 72 + ssg * 8)       = ka;
        *(int4*)(Kb + srow * 72 + (ssg + 4) * 8) = kb;
        {
            ushort* vrow = Vt + srow * 72;
            *(uint2*)(vrow + sA)      = (uint2){(uint32_t)va.x, (uint32_t)va.y};
            *(uint2*)(vrow + sB)      = (uint2){(uint32_t)va.z, (uint32_t)va.w};
            *(uint2*)(vrow + 32 + sA) = (uint2){(uint32_t)vb.x, (uint32_t)vb.y};
            *(uint2*)(vrow + 32 + sB) = (uint2){(uint32_t)vb.z, (uint32_t)vb.w};
        }
        __syncthreads();

        if (kt + 64 < kt0 + Ls / 2) {
            const ushort* kp = kg + (size_t)(kt + 64) * RS;
            const ushort* vp = vg + (kt + 64);
            ka = *(const int4*)(kp + ssg * 8);
            kb = *(const int4*)(kp + (ssg + 4) * 8);
            va = *(const int4*)(vp + ssg * 8);
            vb = *(const int4*)(vp + (ssg + 4) * 8);
        }

        f32x4 s[4][2];
        #pragma unroll
        for (int ks = 0; ks < 2; ++ks)
            #pragma unroll
            for (int mt = 0; mt < 4; ++mt) {
                bf16x8 kf = *(const bf16x8*)(Kb + (mt * 16 + lr) * 72 + ks * 32 + lq * 8);
                #pragma unroll
                for (int qh = 0; qh < 2; ++qh)
                    s[mt][qh] = __builtin_amdgcn_mfma_f32_16x16x32_bf16(
                        kf, qf[ks][qh], ks == 0 ? z4 : s[mt][qh], 0, 0, 0);
            }

        uint2 pb[4][2];
        #pragma unroll
        for (int mt = 0; mt < 4; ++mt)
            #pragma unroll
            for (int qh = 0; qh < 2; ++qh) {
                float p0 = EXP2(s[mt][qh][0]);
                float p1 = EXP2(s[mt][qh][1]);
                float p2 = EXP2(s[mt][qh][2]);
                float p3 = EXP2(s[mt][qh][3]);
                uint32_t w0, w1;
                asm("v_cvt_pk_bf16_f32 %0, %1, %2" : "=v"(w0) : "v"(p0), "v"(p1));
                asm("v_cvt_pk_bf16_f32 %0, %1, %2" : "=v"(w1) : "v"(p2), "v"(p3));
                pb[mt][qh].x = w0;
                pb[mt][qh].y = w1;
            }

        #pragma unroll
        for (int ks = 0; ks < 2; ++ks) {
            bf16x8 pf[2];
            #pragma unroll
            for (int qh = 0; qh < 2; ++qh) {
                uint4 u = (uint4){pb[2 * ks][qh].x, pb[2 * ks][qh].y,
                                  pb[2 * ks + 1][qh].x, pb[2 * ks + 1][qh].y};
                pf[qh] = __builtin_bit_cast(bf16x8, u);
            }
            #pragma unroll
            for (int dt = 0; dt < 4; ++dt) {
                bf16x8 vf = *(const bf16x8*)(Vt + (dt * 16 + lr) * 72 + ks * 32 + lq * 8);
                #pragma unroll
                for (int qh = 0; qh < 2; ++qh)
                    o[dt][qh] = __builtin_amdgcn_mfma_f32_16x16x32_bf16(
                        vf, pf[qh], o[dt][qh], 0, 0, 0);
            }
            #pragma unroll
            for (int qh = 0; qh < 2; ++qh)
                dacc[qh] = __builtin_amdgcn_mfma_f32_16x16x32_bf16(
                    onesf, pf[qh], dacc[qh], 0, 0, 0);
        }
    }

    const int c = wv * 64 + lane;
    __syncthreads();
    if (g == 1) {
        #pragma unroll
        for (int dt = 0; dt < 4; ++dt)
            #pragma unroll
            for (int qh = 0; qh < 2; ++qh)
                #pragma unroll
                for (int r = 0; r < 4; ++r)
                    cmb[dt * 8 + qh * 4 + r][c] = o[dt][qh][r];
        cmb[32][c] = dacc[0][0];
        cmb[33][c] = dacc[1][0];
    }
    __syncthreads();
    if (g == 0) {
        #pragma unroll
        for (int dt = 0; dt < 4; ++dt)
            #pragma unroll
            for (int qh = 0; qh < 2; ++qh)
                #pragma unroll
                for (int r = 0; r < 4; ++r)
                    o[dt][qh][r] += cmb[dt * 8 + qh * 4 + r][c];
        const float d0 = dacc[0][0] + cmb[32][c];
        const float d1 = dacc[1][0] + cmb[33][c];
        #pragma unroll
        for (int qh = 0; qh < 2; ++qh) {
            const float inv = 1.0f / (qh == 0 ? d0 : d1);
            ushort* orow = out + (size_t)(n * Ls + q0 + qh * 16 + lr) * Dm + h * HDd;
            #pragma unroll
            for (int dt = 0; dt < 4; ++dt) {
                ushort4 ob;
                ushort* op = (ushort*)&ob;
                #pragma unroll
                for (int r = 0; r < 4; ++r) op[r] = f2bf(o[dt][qh][r] * inv);
                *(ushort4*)(orow + dt * 16 + lq * 4) = ob;
            }
        }
    }
}

// ---------------------------------------------------------------------------
// out = LayerNorm(sum_{p<NP} part[p] + bias + other) * gamma + beta.
// ---------------------------------------------------------------------------
template <int NP, int OTHER_BF16, int OUT_F32>
__global__ __launch_bounds__(256) void addn_ln(
    const ushort* __restrict__ part, const void* __restrict__ other,
    const float* __restrict__ bias,
    const float* __restrict__ gamma, const float* __restrict__ beta,
    float* __restrict__ outf, ushort* __restrict__ outb)
{
    const int row = blockIdx.x;
    const int tid = threadIdx.x;

    float4 bv = ((const float4*)bias)[tid];
    float v[4];
    if (OTHER_BF16) {
        ushort4 u = ((const ushort4*)((const ushort*)other + (size_t)row * Dm))[tid];
        v[0] = b2f(u.x) + bv.x; v[1] = b2f(u.y) + bv.y;
        v[2] = b2f(u.z) + bv.z; v[3] = b2f(u.w) + bv.w;
    } else {
        float4 f = ((const float4*)((const float*)other + (size_t)row * Dm))[tid];
        v[0] = f.x + bv.x; v[1] = f.y + bv.y; v[2] = f.z + bv.z; v[3] = f.w + bv.w;
    }
    #pragma unroll
    for (int pp = 0; pp < NP; ++pp) {
        ushort4 u = ((const ushort4*)(part + (size_t)pp * Mrows * Dm
                                           + (size_t)row * Dm))[tid];
        v[0] += b2f(u.x); v[1] += b2f(u.y); v[2] += b2f(u.z); v[3] += b2f(u.w);
    }

    float s  = v[0] + v[1] + v[2] + v[3];
    float sq = v[0]*v[0] + v[1]*v[1] + v[2]*v[2] + v[3]*v[3];

    __shared__ float red[8];
    #pragma unroll
    for (int off = 32; off > 0; off >>= 1) {
        s  += __shfl_down(s, off);
        sq += __shfl_down(sq, off);
    }
    const int wv = tid >> 6;
    if ((tid & 63) == 0) { red[wv] = s; red[4 + wv] = sq; }
    __syncthreads();
    s  = red[0] + red[1] + red[2] + red[3];
    sq = red[4] + red[5] + red[6] + red[7];

    const float mu  = s * (1.0f / Dm);
    const float var = sq * (1.0f / Dm) - mu * mu;
    const float inv = rsqrtf(var + 1e-5f);

    const float4 g  = ((const float4*)gamma)[tid];
    const float4 be = ((const float4*)beta)[tid];
    float ov[4];
    ov[0] = (v[0] - mu) * inv * g.x + be.x;
    ov[1] = (v[1] - mu) * inv * g.y + be.y;
    ov[2] = (v[2] - mu) * inv * g.z + be.z;
    ov[3] = (v[3] - mu) * inv * g.w + be.w;
    if (OUT_F32) {
        float4 o4 = {ov[0], ov[1], ov[2], ov[3]};
        ((float4*)(outf + (size_t)row * Dm))[tid] = o4;
    } else {
        uint2 ob;
        ob.x = (uint32_t)f2bf(ov[0]) | ((uint32_t)f2bf(ov[1]) << 16);
        ob.y = (uint32_t)f2bf(ov[2]) | ((uint32_t)f2bf(ov[3]) << 16);
        *(uint2*)(outb + (size_t)row * Dm + tid * 4) = ob;
    }
}

// ---------------------------------------------------------------------------
extern "C" void kernel_launch(void* const* d_in, const int* in_sizes, int n_in,
                              void* d_out, int out_size, void* d_ws, size_t ws_size,
                              hipStream_t stream)
{
    const float* x     = (const float*)d_in[0];
    const float* w_qkv = (const float*)d_in[1];
    const float* b_qkv = (const float*)d_in[2];
    const float* w_o   = (const float*)d_in[3];
    const float* b_o   = (const float*)d_in[4];
    const float* g1    = (const float*)d_in[5];
    const float* be1   = (const float*)d_in[6];
    const float* w1    = (const float*)d_in[7];
    const float* b1    = (const float*)d_in[8];
    const float* w2    = (const float*)d_in[9];
    const float* b2    = (const float*)d_in[10];
    const float* g2    = (const float*)d_in[11];
    const float* be2   = (const float*)d_in[12];
    float* out = (float*)d_out;

    // Workspace. part4 = 4 contiguous 8MB bf16 partial slots:
    //   slots 0,1: proj / ff2 split-K partials
    //   slot 2:    attnb  (dead once proj consumed it -> ff2 partial z=2)
    //   slot 3:    xb     (dead once qkv consumed it  -> ff2 partial z=3)
    char* p = (char*)d_ws;
    ushort* part4 = (ushort*)p;  p += (size_t)4 * Mrows * Dm * 2;   // 32 MB
    ushort* qkvb  = (ushort*)p;  p += (size_t)Mrows * 3 * Dm * 2;
    ushort* hb    = (ushort*)p;  p += (size_t)Mrows * Dm * 2;
    ushort* ffb   = (ushort*)p;  p += (size_t)Mrows * FFd * 2;
    ushort* wqkvT = (ushort*)p;  p += (size_t)(3 * Dm) * Dm * 2;
    ushort* woT   = (ushort*)p;  p += (size_t)Dm * Dm * 2;
    ushort* w1T   = (ushort*)p;  p += (size_t)FFd * Dm * 2;
    ushort* w2T   = (ushort*)p;  p += (size_t)Dm * FFd * 2;
    ushort* vTg   = (ushort*)p;  p += (size_t)Mrows * Dm * 2;

    ushort* attnb = part4 + (size_t)2 * Mrows * Dm;
    ushort* xb    = part4 + (size_t)3 * Mrows * Dm;

    // fused convert + weight transposes (1 launch instead of 5)
    prep<<<dim3(16384), dim3(256), 0, stream>>>(
        x, xb, w_qkv, wqkvT, w_o, woT, w1, w1T, w2, w2T);

    // qkv = x @ w_qkv + b_qkv; TN=96 -> 4 blocks/CU. Q,K -> qkvb, V -> vTg.
    gemm_mfma<96, 0, 1, 1><<<dim3(3 * Dm / 96, Mrows / 128), dim3(256), 0, stream>>>(
        xb, wqkvT, b_qkv, qkvb, vTg, Mrows, 3 * Dm, Dm);

    // attn: intra-block KV-split, direct bf16 output
    attn_mfma<<<dim3(Ls / 128, Hh, Nb), dim3(512), 0, stream>>>(qkvb, vTg, attnb);

    // proj partials = attn @ w_o (split-K 2 -> slots 0,1)
    gemm_mfma<64, 0, 0, 2><<<dim3(Dm / 64, Mrows / 128, 2), dim3(256), 0, stream>>>(
        attnb, woT, nullptr, part4, nullptr, Mrows, Dm, Dm);

    // h = LN(p0 + p1 + b_o + x) -> bf16
    addn_ln<2, 0, 0><<<dim3(Mrows), dim3(256), 0, stream>>>(
        part4, x, b_o, g1, be1, nullptr, hb);

    // ff = relu(h @ w1 + b1): 256^2 phase-split pipeline, grid 256 = 1/CU
    gemm256<1, 1><<<dim3(FFd / 256, Mrows / 256), dim3(512), 0, stream>>>(
        hb, w1T, b1, ffb, Mrows, FFd, Dm);

    // ff2 partials = ff @ w2 (256^2 pipeline, split-K 4 -> slots 0..3)
    gemm256<0, 4><<<dim3(Dm / 256, Mrows / 256, 4), dim3(512), 0, stream>>>(
        ffb, w2T, nullptr, part4, Mrows, Dm, FFd);

    // out = LN(p0 + p1 + p2 + p3 + b2 + h) -> fp32
    addn_ln<4, 1, 1><<<dim3(Mrows), dim3(256), 0, stream>>>(
        part4, hb, b2, g2, be2, out, nullptr);
}